// Round 2
// 848.366 us; speedup vs baseline: 1.1807x; 1.1807x over previous
//
#include <hip/hip_runtime.h>

// Problem constants (from reference)
#define NN   100000      // nodes
#define NE   1600000     // edges
#define DD   64          // node feature dim
#define ECH  16          // edge channels
#define EMBD 128
#define G1D  512
#define G2D  64000
#define NGR  100         // graphs
#define NM1D 128

typedef __attribute__((ext_vector_type(8))) short short8;
typedef __attribute__((ext_vector_type(4))) float float4v;

__device__ __forceinline__ float bf2f(unsigned short u) {
    union { unsigned int i; float f; } v; v.i = ((unsigned int)u) << 16; return v.f;
}
__device__ __forceinline__ unsigned short f2bf(float f) {
    union { unsigned int i; float f; } v; v.f = f;
    unsigned int u = v.i;
    return (unsigned short)((u + 0x7fffu + ((u >> 16) & 1u)) >> 16);
}
__device__ __forceinline__ float blo(unsigned int d) {
    union { unsigned int i; float f; } v; v.i = d << 16; return v.f;
}
__device__ __forceinline__ float bhi(unsigned int d) {
    union { unsigned int i; float f; } v; v.i = d & 0xffff0000u; return v.f;
}
__device__ __forceinline__ int iclamp(int v, int lo, int hi) {
    return v < lo ? lo : (v > hi ? hi : v);
}

// ---- dtype-generic accessors (T = float or unsigned short[bf16]) ----
__device__ __forceinline__ float ldf(const float* p, size_t i) { return p[i]; }
__device__ __forceinline__ float ldf(const unsigned short* p, size_t i) { return bf2f(p[i]); }
__device__ __forceinline__ unsigned short ldbf(const float* p, size_t i) { return f2bf(p[i]); }
__device__ __forceinline__ unsigned short ldbf(const unsigned short* p, size_t i) { return p[i]; }
__device__ __forceinline__ void stf(float* p, size_t i, float v) { p[i] = v; }
__device__ __forceinline__ void stf(unsigned short* p, size_t i, float v) { p[i] = f2bf(v); }
__device__ __forceinline__ void ld16v(const float* p, float* o) {
    const float4* q = (const float4*)p;
    float4 a = q[0], b = q[1], c = q[2], d = q[3];
    o[0]=a.x; o[1]=a.y; o[2]=a.z; o[3]=a.w;
    o[4]=b.x; o[5]=b.y; o[6]=b.z; o[7]=b.w;
    o[8]=c.x; o[9]=c.y; o[10]=c.z; o[11]=c.w;
    o[12]=d.x; o[13]=d.y; o[14]=d.z; o[15]=d.w;
}
__device__ __forceinline__ void ld16v(const unsigned short* p, float* o) {
    const uint4* q = (const uint4*)p;
    uint4 a = q[0], b = q[1];
    o[0]=blo(a.x); o[1]=bhi(a.x); o[2]=blo(a.y); o[3]=bhi(a.y);
    o[4]=blo(a.z); o[5]=bhi(a.z); o[6]=blo(a.w); o[7]=bhi(a.w);
    o[8]=blo(b.x); o[9]=bhi(b.x); o[10]=blo(b.y); o[11]=bhi(b.y);
    o[12]=blo(b.z); o[13]=bhi(b.z); o[14]=blo(b.w); o[15]=bhi(b.w);
}
template <typename T> struct tagof;
template <> struct tagof<float> { static constexpr int v = 0; };
template <> struct tagof<unsigned short> { static constexpr int v = 1; };

#define MFMA(a, b, c) __builtin_amdgcn_mfma_f32_16x16x32_bf16((a), (b), (c), 0, 0, 0)

// ---------------- runtime dtype detection (parallel, 1 wave) ----------------
__global__ __launch_bounds__(64) void k_detect(const unsigned short* __restrict__ embu,
                                               const int* __restrict__ eidx,
                                               int* __restrict__ dtf) {
    int lane = threadIdx.x;
    int sane = 0;
    for (int i = lane; i < 512; i += 64) {
        unsigned short x = embu[i];
        int e = (x >> 7) & 0xFF;
        if (x == 0 || (e >= 97 && e <= 157)) sane++;
    }
    for (int m = 32; m >= 1; m >>= 1) sane += __shfl_xor(sane, m);
    int oddNZ = 0, evenNZ = 0;
    for (int i = lane; i < 256; i += 64) {
        if (eidx[2 * i + 1] != 0) oddNZ = 1;
        if (eidx[2 * i] != 0) evenNZ = 1;
    }
    unsigned long long bo = __ballot(oddNZ);
    unsigned long long be = __ballot(evenNZ);
    if (lane == 0) {
        dtf[0] = (sane >= 461) ? 1 : 0;
        dtf[1] = (bo == 0ULL && be != 0ULL) ? 1 : 0;
    }
}
__device__ __forceinline__ int ld_src(const int* e, int f, int i) {
    int v = f ? e[2 * i] : e[i];
    return iclamp(v, 0, NN - 1);
}
__device__ __forceinline__ int ld_dst(const int* e, int f, int i) {
    int v = f ? e[2 * (NE + i)] : e[NE + i];
    return iclamp(v, 0, NN - 1);
}

// ---------------- decoder MLP layer 1 ----------------
template <typename T>
__global__ __launch_bounds__(256) void k_dec1(const int* __restrict__ dtf,
                                              const T* __restrict__ emb,
                                              const T* __restrict__ Wg1,
                                              const T* __restrict__ bg1,
                                              unsigned short* __restrict__ h) {
    if (dtf[0] != tagof<T>::v) return;
    __shared__ float es[EMBD];
    int m = blockIdx.x, t = threadIdx.x;
    if (t < EMBD) es[t] = ldf(emb, (size_t)m * EMBD + t);
    __syncthreads();
    for (int n = t; n < G1D; n += 256) {
        float acc = ldf(bg1, n);
        for (int k = 0; k < EMBD; k++) acc += es[k] * ldf(Wg1, (size_t)k * G1D + n);
        h[m * G1D + n] = f2bf(fmaxf(acc, 0.f));
    }
}

// ---------------- decoder MLP layer 2 (MFMA) ----------------
template <typename T>
__global__ __launch_bounds__(256) void k_dec2(const int* __restrict__ dtf,
                                              const unsigned short* __restrict__ h,
                                              const T* __restrict__ Wg2,
                                              const T* __restrict__ bg2,
                                              unsigned short* __restrict__ x) {
    if (dtf[0] != tagof<T>::v) return;
    int wid = threadIdx.x >> 6, lane = threadIdx.x & 63;
    int q = lane >> 4, l16 = lane & 15;
    int n = blockIdx.x * 64 + wid * 16 + l16;
    float4v acc[7];
    for (int mt = 0; mt < 7; mt++) for (int i = 0; i < 4; i++) acc[mt][i] = 0.f;
    for (int kt = 0; kt < 16; kt++) {
        int k0 = kt * 32 + q * 8;
        short8 bf;
        for (int j = 0; j < 8; j++) bf[j] = (short)ldbf(Wg2, (size_t)(k0 + j) * G2D + n);
        for (int mt = 0; mt < 7; mt++) {
            int row = mt * 16 + l16;
            short8 af;
            if (row < NGR) {
                af = *(const short8*)(h + row * G1D + k0);
            } else {
                for (int j = 0; j < 8; j++) af[j] = 0;
            }
            acc[mt] = MFMA(af, bf, acc[mt]);
        }
    }
    float bias = ldf(bg2, n);
    for (int mt = 0; mt < 7; mt++) {
        for (int i = 0; i < 4; i++) {
            int m = mt * 16 + q * 4 + i;
            if (m < NGR) x[(size_t)m * G2D + n] = f2bf(acc[mt][i] + bias);
        }
    }
}

// ---------------- CSR build ----------------
__global__ __launch_bounds__(256) void k_zero(int* __restrict__ deg) {
    int i = blockIdx.x * 256 + threadIdx.x;
    if (i < NN) deg[i] = 0;
}
__global__ __launch_bounds__(256) void k_hist(const int* __restrict__ eidx, const int* __restrict__ dtf,
                                              int* __restrict__ deg) {
    int e = blockIdx.x * 256 + threadIdx.x;   // grid exact
    int f = dtf[1];
    atomicAdd(&deg[ld_dst(eidx, f, e)], 1);
}
__global__ __launch_bounds__(256) void k_scan1(const int* __restrict__ deg, int* __restrict__ bsum) {
    __shared__ int r[256];
    int t = threadIdx.x, i0 = blockIdx.x * 512 + 2 * t;
    int e0 = (i0 < NN) ? deg[i0] : 0;
    int e1 = (i0 + 1 < NN) ? deg[i0 + 1] : 0;
    r[t] = e0 + e1;
    __syncthreads();
    for (int off = 128; off > 0; off >>= 1) {
        if (t < off) r[t] += r[t + off];
        __syncthreads();
    }
    if (t == 0) bsum[blockIdx.x] = r[0];
}
__global__ __launch_bounds__(256) void k_scan2(int* __restrict__ bsum, int nblk) {
    __shared__ int sc[256];
    int t = threadIdx.x;
    int v = (t < nblk) ? bsum[t] : 0;
    sc[t] = v;
    __syncthreads();
    for (int off = 1; off < 256; off <<= 1) {
        int u = (t >= off) ? sc[t - off] : 0;
        __syncthreads();
        sc[t] += u;
        __syncthreads();
    }
    if (t < nblk) bsum[t] = sc[t] - v;   // exclusive
}
__global__ __launch_bounds__(256) void k_scan3(const int* __restrict__ deg, const int* __restrict__ bsum,
                                               int* __restrict__ ptr, int* __restrict__ cur) {
    __shared__ int sc[256];
    int t = threadIdx.x, i0 = blockIdx.x * 512 + 2 * t;
    int e0 = (i0 < NN) ? deg[i0] : 0;
    int e1 = (i0 + 1 < NN) ? deg[i0 + 1] : 0;
    int s = e0 + e1;
    sc[t] = s;
    __syncthreads();
    for (int off = 1; off < 256; off <<= 1) {
        int v = (t >= off) ? sc[t - off] : 0;
        __syncthreads();
        sc[t] += v;
        __syncthreads();
    }
    int excl = sc[t] - s;
    int p0 = bsum[blockIdx.x] + excl;
    if (i0 < NN)     { ptr[i0] = p0;          cur[i0] = p0; }
    if (i0 + 1 < NN) { ptr[i0 + 1] = p0 + e0; cur[i0 + 1] = p0 + e0; }
    if (blockIdx.x == 0 && t == 0) ptr[NN] = NE;
}
// csr.x stores the Y-ROW BYTE OFFSET (clamped src * DD * 2) — saves per-edge
// clamp+shift in the aggregation kernels.
__global__ __launch_bounds__(256) void k_fill(const int* __restrict__ eidx, const int* __restrict__ dtf,
                                              int* __restrict__ cur, int2* __restrict__ csr) {
    int e = blockIdx.x * 256 + threadIdx.x;   // grid exact
    int f = dtf[1];
    int src = ld_src(eidx, f, e);
    int dst = ld_dst(eidx, f, e);
    int pos = atomicAdd(&cur[dst], 1);
    pos = iclamp(pos, 0, NE - 1);
    csr[pos] = make_int2(src * (DD * 2), e);
}

// ---------------- permute edge_attr into CSR order (bf16-packed) ----------------
template <typename T>
__global__ __launch_bounds__(256) void k_eaperm(const int* __restrict__ dtf,
                                                const int2* __restrict__ csr,
                                                const T* __restrict__ ea,
                                                unsigned short* __restrict__ eaP) {
    if (dtf[0] != tagof<T>::v) return;
    int p = blockIdx.x * 256 + threadIdx.x;   // grid exact: NE/256
    int eid = iclamp(csr[p].y, 0, NE - 1);
    float ev[16];
    ld16v(ea + (size_t)eid * ECH, ev);
    unsigned int wv[8];
    for (int i = 0; i < 8; i++)
        wv[i] = (unsigned int)f2bf(ev[2 * i]) | ((unsigned int)f2bf(ev[2 * i + 1]) << 16);
    uint4* op = (uint4*)(eaP + (size_t)p * ECH);
    op[0] = make_uint4(wv[0], wv[1], wv[2], wv[3]);
    op[1] = make_uint4(wv[4], wv[5], wv[6], wv[7]);
}

// ---------------- MFMA edge aggregation (PERM path) ----------------
// Per wave: one dst node. Edges processed in batches of 16:
//   P[16e][64c] = eaP[16e][16k] @ mW[DD..DD+16][64]   (4x mfma 16x16x32, K padded)
//   z = relu(P + y[src] + mb), acc[c] += z, summed over edge rows.
// Fragment maps identical to gemm_node (harness-verified):
//   A: row=l16, k=q*8+j   B: k=q*8+j, col=l16   D: row=q*4+i, col=l16
template <typename T>
__global__ __launch_bounds__(256) void k_agg_mfma(const int* __restrict__ dtf,
                                                  const int2* __restrict__ csr,
                                                  const int* __restrict__ ptr,
                                                  const unsigned short* __restrict__ y,
                                                  const unsigned short* __restrict__ eaP,
                                                  const T* __restrict__ mW,
                                                  const T* __restrict__ mb,
                                                  unsigned short* __restrict__ agg) {
    if (dtf[0] != tagof<T>::v) return;
    int nid = blockIdx.x * 4 + (threadIdx.x >> 6);
    int lane = threadIdx.x & 63;
    int q = lane >> 4, l16 = lane & 15;

    // B fragments: 4 col-tiles of mW rows [DD, DD+16); k>=16 zeroed (q>=2)
    short8 bfr[4];
    #pragma unroll
    for (int nt = 0; nt < 4; nt++) {
        short8 b;
        #pragma unroll
        for (int j = 0; j < 8; j++) b[j] = 0;
        if (q < 2) {
            #pragma unroll
            for (int j = 0; j < 8; j++)
                b[j] = (short)ldbf(mW, (size_t)(DD + q * 8 + j) * DD + nt * 16 + l16);
        }
        bfr[nt] = b;
    }
    // per-lane bias for this lane's 4 columns (col = nt*16 + l16)
    float mbc[4];
    #pragma unroll
    for (int nt = 0; nt < 4; nt++) mbc[nt] = ldf(mb, nt * 16 + l16);

    int s = iclamp(ptr[nid], 0, NE);
    int e = iclamp(ptr[nid + 1], s, NE);

    float acc[4] = {0.f, 0.f, 0.f, 0.f};
    const float4v z4 = {0.f, 0.f, 0.f, 0.f};

    for (int t = s; t < e; t += 16) {
        // A fragment: edge row t+l16, k=q*8+j (zero outside tail / q>=2)
        short8 af;
        #pragma unroll
        for (int j = 0; j < 8; j++) af[j] = 0;
        int erow = t + l16;
        if (erow < e && q < 2)
            af = *(const short8*)(eaP + (size_t)erow * ECH + q * 8);

        // this lane's 4 edge rows: indices t+q*4+i
        int off[4]; bool val[4];
        #pragma unroll
        for (int i = 0; i < 4; i++) {
            int idx = t + q * 4 + i;
            val[i] = idx < e;
            int cidx = idx < e ? idx : (e - 1);   // loop guarantees e > s >= 0
            off[i] = csr[cidx].x;                  // y-row byte offset
        }

        #pragma unroll
        for (int nt = 0; nt < 4; nt++) {
            float4v p = MFMA(af, bfr[nt], z4);
            int colb = (nt * 16 + l16) * 2;
            #pragma unroll
            for (int i = 0; i < 4; i++) {
                float yv = bf2f(*(const unsigned short*)((const char*)y + (unsigned int)(off[i] + colb)));
                float z = fmaxf(p[i] + yv + mbc[nt], 0.f);
                acc[nt] += val[i] ? z : 0.f;
            }
        }
    }

    // reduce edge-row partials across the 4 q-groups (same l16, same col)
    #pragma unroll
    for (int nt = 0; nt < 4; nt++) {
        acc[nt] += __shfl_xor(acc[nt], 16);
        acc[nt] += __shfl_xor(acc[nt], 32);
    }
    // lane (q,l16) writes col q*16+l16 == lane: coalesced row store
    float r = (q == 0) ? acc[0] : (q == 1) ? acc[1] : (q == 2) ? acc[2] : acc[3];
    agg[(size_t)nid * DD + lane] = f2bf(r);
}

// ---------------- scalar edge aggregation (fallback, no eaP) ----------------
template <typename T>
__global__ __launch_bounds__(256) void k_agg(const int* __restrict__ dtf,
                                             const int2* __restrict__ csr, const int* __restrict__ ptr,
                                             const unsigned short* __restrict__ y,
                                             const T* __restrict__ ea,
                                             const T* __restrict__ mW,
                                             const T* __restrict__ mb,
                                             unsigned short* __restrict__ agg) {
    if (dtf[0] != tagof<T>::v) return;
    int nid = blockIdx.x * 4 + (threadIdx.x >> 6);
    int lane = threadIdx.x & 63;
    float wk[16];
    for (int k = 0; k < 16; k++) wk[k] = ldf(mW, (size_t)(DD + k) * DD + lane);
    float mbv = ldf(mb, lane);
    int s = iclamp(ptr[nid], 0, NE);
    int e = iclamp(ptr[nid + 1], s, NE);
    const char* yl = (const char*)y + (size_t)lane * 2;   // csr.x is a byte offset
    float acc = 0.f;
    int t = s;
    for (; t + 2 <= e; t += 2) {
        int2 p0 = csr[t], p1 = csr[t + 1];
        float y0 = bf2f(*(const unsigned short*)(yl + (unsigned int)p0.x));
        float y1 = bf2f(*(const unsigned short*)(yl + (unsigned int)p1.x));
        float e0[16], e1[16];
        ld16v(ea + (size_t)iclamp(p0.y, 0, NE - 1) * ECH, e0);
        ld16v(ea + (size_t)iclamp(p1.y, 0, NE - 1) * ECH, e1);
        float z0 = mbv + y0, z1 = mbv + y1;
        #pragma unroll
        for (int k = 0; k < 16; k++) { z0 = fmaf(e0[k], wk[k], z0); z1 = fmaf(e1[k], wk[k], z1); }
        acc += fmaxf(z0, 0.f) + fmaxf(z1, 0.f);
    }
    for (; t < e; ++t) {
        int2 p = csr[t];
        float yv = bf2f(*(const unsigned short*)(yl + (unsigned int)p.x));
        float ev[16];
        ld16v(ea + (size_t)iclamp(p.y, 0, NE - 1) * ECH, ev);
        float z = mbv + yv;
        #pragma unroll
        for (int k = 0; k < 16; k++) z = fmaf(ev[k], wk[k], z);
        acc += fmaxf(z, 0.f);
    }
    agg[(size_t)nid * DD + lane] = f2bf(acc);
}

// ---------------- generic skinny MFMA GEMM over node rows ----------------
template <typename T, int KT1, int KT2, int NT, bool RELU, bool HASBIAS>
__global__ __launch_bounds__(256) void gemm_node(const int* __restrict__ dtf,
                                                 const unsigned short* __restrict__ A1,
                                                 const unsigned short* __restrict__ A2,
                                                 const T* __restrict__ W,
                                                 const T* __restrict__ bias,
                                                 unsigned short* __restrict__ out) {
    if (dtf[0] != tagof<T>::v) return;
    constexpr int KT = KT1 + KT2;
    constexpr int N = NT * 16;
    int wid = threadIdx.x >> 6, lane = threadIdx.x & 63;
    int q = lane >> 4, l16 = lane & 15;
    int mt = blockIdx.x * 4 + wid;
    int m0 = mt * 16;
    if (m0 >= NN) return;
    short8 bfr[KT][NT];
    for (int kt = 0; kt < KT; kt++)
        for (int nt = 0; nt < NT; nt++)
            for (int j = 0; j < 8; j++)
                bfr[kt][nt][j] = (short)ldbf(W, (size_t)(kt * 32 + q * 8 + j) * N + nt * 16 + l16);
    float4v acc[NT];
    for (int nt = 0; nt < NT; nt++) for (int i = 0; i < 4; i++) acc[nt][i] = 0.f;

    const unsigned short* a1p = A1 + (size_t)(m0 + l16) * (KT1 * 32) + q * 8;
    for (int kt = 0; kt < KT1; kt++) {
        short8 af = *(const short8*)(a1p + kt * 32);
        for (int nt = 0; nt < NT; nt++) acc[nt] = MFMA(af, bfr[kt][nt], acc[nt]);
    }
    if constexpr (KT2 > 0) {
        const unsigned short* a2p = A2 + (size_t)(m0 + l16) * (KT2 * 32) + q * 8;
        for (int kt = 0; kt < KT2; kt++) {
            short8 af = *(const short8*)(a2p + kt * 32);
            for (int nt = 0; nt < NT; nt++) acc[nt] = MFMA(af, bfr[KT1 + kt][nt], acc[nt]);
        }
    }
    for (int nt = 0; nt < NT; nt++) {
        int n = nt * 16 + l16;
        float b = HASBIAS ? ldf(bias, n) : 0.f;
        for (int i = 0; i < 4; i++) {
            float v = acc[nt][i] + b;
            if (RELU) v = fmaxf(v, 0.f);
            out[(size_t)(m0 + q * 4 + i) * N + n] = f2bf(v);
        }
    }
}

// ---------------- fused node MLP ----------------
template <typename T>
__global__ __launch_bounds__(256) void k_mlp_out(const int* __restrict__ dtf,
                                                 const unsigned short* __restrict__ A,
                                                 const T* __restrict__ nW1,
                                                 const T* __restrict__ nb1,
                                                 const T* __restrict__ nW2,
                                                 const T* __restrict__ nb2,
                                                 T* __restrict__ out) {
    if (dtf[0] != tagof<T>::v) return;
    constexpr int NT = 8, N = 128;
    int wid = threadIdx.x >> 6, lane = threadIdx.x & 63;
    int q = lane >> 4, l16 = lane & 15;
    int mt = blockIdx.x * 4 + wid;
    int m0 = mt * 16;
    if (m0 >= NN) return;
    short8 bfr[2][NT];
    float cb[NT], w2r[NT][3];
    for (int kt = 0; kt < 2; kt++)
        for (int nt = 0; nt < NT; nt++)
            for (int j = 0; j < 8; j++)
                bfr[kt][nt][j] = (short)ldbf(nW1, (size_t)(kt * 32 + q * 8 + j) * N + nt * 16 + l16);
    for (int nt = 0; nt < NT; nt++) {
        int col = nt * 16 + l16;
        cb[nt] = ldf(nb1, col);
        for (int j = 0; j < 3; j++) w2r[nt][j] = ldf(nW2, (size_t)col * 3 + j);
    }
    float4v acc[NT];
    for (int nt = 0; nt < NT; nt++) for (int i = 0; i < 4; i++) acc[nt][i] = 0.f;
    const unsigned short* ap = A + (size_t)(m0 + l16) * DD + q * 8;
    for (int kt = 0; kt < 2; kt++) {
        short8 af = *(const short8*)(ap + kt * 32);
        for (int nt = 0; nt < NT; nt++) acc[nt] = MFMA(af, bfr[kt][nt], acc[nt]);
    }
    float b0 = ldf(nb2, 0), b1 = ldf(nb2, 1), b2 = ldf(nb2, 2);
    for (int i = 0; i < 4; i++) {
        float p0 = 0.f, p1 = 0.f, p2 = 0.f;
        for (int nt = 0; nt < NT; nt++) {
            float v = fmaxf(acc[nt][i] + cb[nt], 0.f);
            p0 += v * w2r[nt][0];
            p1 += v * w2r[nt][1];
            p2 += v * w2r[nt][2];
        }
        for (int m = 1; m < 16; m <<= 1) {
            p0 += __shfl_xor(p0, m);
            p1 += __shfl_xor(p1, m);
            p2 += __shfl_xor(p2, m);
        }
        if (l16 == 0) {
            size_t row = (size_t)(m0 + q * 4 + i) * 3;
            stf(out, row + 0, p0 + b0);
            stf(out, row + 1, p1 + b1);
            stf(out, row + 2, p2 + b2);
        }
    }
}

// ---------------- typed pipeline launcher ----------------
template <typename T, bool PERM>
static void launch_typed(void* const* d_in, void* d_out, hipStream_t stream,
                         const int* dtf, const int2* csr, const int* ptr,
                         const unsigned short* eaP,
                         unsigned short* nA, unsigned short* nB, unsigned short* nG,
                         unsigned short* hb, int GEMM_BLKS) {
    const T* emb = (const T*)d_in[0];
    const T* ea  = (const T*)d_in[2];
    const T* Wg1 = (const T*)d_in[3];  const T* bg1 = (const T*)d_in[4];
    const T* Wg2 = (const T*)d_in[5];  const T* bg2 = (const T*)d_in[6];
    const T* mW0 = (const T*)d_in[7];  const T* mb0 = (const T*)d_in[8];
    const T* uW0 = (const T*)d_in[9];  const T* ub0 = (const T*)d_in[10];
    const T* mW1 = (const T*)d_in[11]; const T* mb1 = (const T*)d_in[12];
    const T* uW1 = (const T*)d_in[13]; const T* ub1 = (const T*)d_in[14];
    const T* nW1 = (const T*)d_in[15]; const T* nb1 = (const T*)d_in[16];
    const T* nW2 = (const T*)d_in[17]; const T* nb2 = (const T*)d_in[18];
    T* out = (T*)d_out;

    k_dec1<T><<<NGR, 256, 0, stream>>>(dtf, emb, Wg1, bg1, hb);
    k_dec2<T><<<G2D / 64, 256, 0, stream>>>(dtf, hb, Wg2, bg2, nA);

    if (PERM) k_eaperm<T><<<NE / 256, 256, 0, stream>>>(dtf, csr, ea, (unsigned short*)eaP);

    gemm_node<T, 2, 0, 4, false, false><<<GEMM_BLKS, 256, 0, stream>>>(dtf, nA, nullptr, mW0, nullptr, nB);
    if (PERM) k_agg_mfma<T><<<NN / 4, 256, 0, stream>>>(dtf, csr, ptr, nB, eaP, mW0, mb0, nG);
    else      k_agg<T><<<NN / 4, 256, 0, stream>>>(dtf, csr, ptr, nB, ea, mW0, mb0, nG);
    gemm_node<T, 2, 2, 4, true, true><<<GEMM_BLKS, 256, 0, stream>>>(dtf, nA, nG, uW0, ub0, nB);

    gemm_node<T, 2, 0, 4, false, false><<<GEMM_BLKS, 256, 0, stream>>>(dtf, nB, nullptr, mW1, nullptr, nA);
    if (PERM) k_agg_mfma<T><<<NN / 4, 256, 0, stream>>>(dtf, csr, ptr, nA, eaP, mW1, mb1, nG);
    else      k_agg<T><<<NN / 4, 256, 0, stream>>>(dtf, csr, ptr, nA, ea, mW1, mb1, nG);
    gemm_node<T, 2, 2, 4, true, true><<<GEMM_BLKS, 256, 0, stream>>>(dtf, nB, nG, uW1, ub1, nA);

    k_mlp_out<T><<<GEMM_BLKS, 256, 0, stream>>>(dtf, nA, nW1, nb1, nW2, nb2, out);
}

extern "C" void kernel_launch(void* const* d_in, const int* in_sizes, int n_in,
                              void* d_out, int out_size, void* d_ws, size_t ws_size,
                              hipStream_t stream) {
    const int* eix = (const int*)d_in[1];

    // workspace carve-up: base ~52.3 MB + optional eaP 51.2 MB
    char* w = (char*)d_ws;
    size_t off = 0;
    auto carve = [&](size_t bytes) { char* p = w + off; off = (off + bytes + 255) & ~(size_t)255; return p; };
    unsigned short* nA = (unsigned short*)carve((size_t)NN * DD * 2);   // 12.8 MB
    unsigned short* nB = (unsigned short*)carve((size_t)NN * DD * 2);   // 12.8 MB
    unsigned short* nG = (unsigned short*)carve((size_t)NN * DD * 2);   // 12.8 MB
    int2* csr = (int2*)carve((size_t)NE * 8);                           // 12.8 MB
    unsigned short* hb = (unsigned short*)carve((size_t)NGR * G1D * 2); // 0.1 MB
    int* deg  = (int*)carve((size_t)NN * 4);
    int* ptr  = (int*)carve((size_t)(NN + 1) * 4);
    int* cur  = (int*)carve((size_t)NN * 4);
    int* bsum = (int*)carve((size_t)256 * 4);
    int* dtf  = (int*)carve(256);
    size_t base_off = off;
    unsigned short* eaP = (unsigned short*)carve((size_t)NE * ECH * 2); // 51.2 MB
    bool perm = (off <= ws_size);           // host-constant branch: graph-safe
    if (!perm) eaP = nullptr, off = base_off;
    (void)in_sizes; (void)n_in; (void)out_size;

    const int SCAN_BLKS = (NN + 511) / 512;   // 196
    const int GEMM_BLKS = (NN / 16 + 3) / 4;  // 1563

    k_detect<<<1, 64, 0, stream>>>((const unsigned short*)d_in[0], eix, dtf);

    // CSR build (dtype-independent)
    k_zero<<<(NN + 255) / 256, 256, 0, stream>>>(deg);
    k_hist<<<NE / 256, 256, 0, stream>>>(eix, dtf, deg);
    k_scan1<<<SCAN_BLKS, 256, 0, stream>>>(deg, bsum);
    k_scan2<<<1, 256, 0, stream>>>(bsum, SCAN_BLKS);
    k_scan3<<<SCAN_BLKS, 256, 0, stream>>>(deg, bsum, ptr, cur);
    k_fill<<<NE / 256, 256, 0, stream>>>(eix, dtf, cur, csr);

    // launch both dtype variants; the wrong one early-exits on dtf[0]
    if (perm) {
        launch_typed<float, true>(d_in, d_out, stream, dtf, csr, ptr, eaP, nA, nB, nG, hb, GEMM_BLKS);
        launch_typed<unsigned short, true>(d_in, d_out, stream, dtf, csr, ptr, eaP, nA, nB, nG, hb, GEMM_BLKS);
    } else {
        launch_typed<float, false>(d_in, d_out, stream, dtf, csr, ptr, nullptr, nA, nB, nG, hb, GEMM_BLKS);
        launch_typed<unsigned short, false>(d_in, d_out, stream, dtf, csr, ptr, nullptr, nA, nB, nG, hb, GEMM_BLKS);
    }
}

// Round 4
// 811.866 us; speedup vs baseline: 1.2338x; 1.0450x over previous
//
#include <hip/hip_runtime.h>

// Problem constants (from reference)
#define NN   100000      // nodes
#define NE   1600000     // edges
#define DD   64          // node feature dim
#define ECH  16          // edge channels
#define EMBD 128
#define G1D  512
#define G2D  64000
#define NGR  100         // graphs
#define NM1D 128

typedef __attribute__((ext_vector_type(8))) short short8;
typedef __attribute__((ext_vector_type(4))) float float4v;

__device__ __forceinline__ float bf2f(unsigned short u) {
    union { unsigned int i; float f; } v; v.i = ((unsigned int)u) << 16; return v.f;
}
__device__ __forceinline__ unsigned short f2bf(float f) {
    union { unsigned int i; float f; } v; v.f = f;
    unsigned int u = v.i;
    return (unsigned short)((u + 0x7fffu + ((u >> 16) & 1u)) >> 16);
}
__device__ __forceinline__ float blo(unsigned int d) {
    union { unsigned int i; float f; } v; v.i = d << 16; return v.f;
}
__device__ __forceinline__ float bhi(unsigned int d) {
    union { unsigned int i; float f; } v; v.i = d & 0xffff0000u; return v.f;
}
__device__ __forceinline__ int iclamp(int v, int lo, int hi) {
    return v < lo ? lo : (v > hi ? hi : v);
}

// ---- dtype-generic accessors (T = float or unsigned short[bf16]) ----
__device__ __forceinline__ float ldf(const float* p, size_t i) { return p[i]; }
__device__ __forceinline__ float ldf(const unsigned short* p, size_t i) { return bf2f(p[i]); }
__device__ __forceinline__ unsigned short ldbf(const float* p, size_t i) { return f2bf(p[i]); }
__device__ __forceinline__ unsigned short ldbf(const unsigned short* p, size_t i) { return p[i]; }
__device__ __forceinline__ void stf(float* p, size_t i, float v) { p[i] = v; }
__device__ __forceinline__ void stf(unsigned short* p, size_t i, float v) { p[i] = f2bf(v); }
__device__ __forceinline__ void ld16v(const float* p, float* o) {
    const float4* q = (const float4*)p;
    float4 a = q[0], b = q[1], c = q[2], d = q[3];
    o[0]=a.x; o[1]=a.y; o[2]=a.z; o[3]=a.w;
    o[4]=b.x; o[5]=b.y; o[6]=b.z; o[7]=b.w;
    o[8]=c.x; o[9]=c.y; o[10]=c.z; o[11]=c.w;
    o[12]=d.x; o[13]=d.y; o[14]=d.z; o[15]=d.w;
}
__device__ __forceinline__ void ld16v(const unsigned short* p, float* o) {
    const uint4* q = (const uint4*)p;
    uint4 a = q[0], b = q[1];
    o[0]=blo(a.x); o[1]=bhi(a.x); o[2]=blo(a.y); o[3]=bhi(a.y);
    o[4]=blo(a.z); o[5]=bhi(a.z); o[6]=blo(a.w); o[7]=bhi(a.w);
    o[8]=blo(b.x); o[9]=bhi(b.x); o[10]=blo(b.y); o[11]=bhi(b.y);
    o[12]=blo(b.z); o[13]=bhi(b.z); o[14]=blo(b.w); o[15]=bhi(b.w);
}
template <typename T> struct tagof;
template <> struct tagof<float> { static constexpr int v = 0; };
template <> struct tagof<unsigned short> { static constexpr int v = 1; };

#define MFMA(a, b, c) __builtin_amdgcn_mfma_f32_16x16x32_bf16((a), (b), (c), 0, 0, 0)

// ---------------- runtime dtype detection (parallel, 1 wave) ----------------
__global__ __launch_bounds__(64) void k_detect(const unsigned short* __restrict__ embu,
                                               const int* __restrict__ eidx,
                                               int* __restrict__ dtf) {
    int lane = threadIdx.x;
    int sane = 0;
    for (int i = lane; i < 512; i += 64) {
        unsigned short x = embu[i];
        int e = (x >> 7) & 0xFF;
        if (x == 0 || (e >= 97 && e <= 157)) sane++;
    }
    for (int m = 32; m >= 1; m >>= 1) sane += __shfl_xor(sane, m);
    int oddNZ = 0, evenNZ = 0;
    for (int i = lane; i < 256; i += 64) {
        if (eidx[2 * i + 1] != 0) oddNZ = 1;
        if (eidx[2 * i] != 0) evenNZ = 1;
    }
    unsigned long long bo = __ballot(oddNZ);
    unsigned long long be = __ballot(evenNZ);
    if (lane == 0) {
        dtf[0] = (sane >= 461) ? 1 : 0;
        dtf[1] = (bo == 0ULL && be != 0ULL) ? 1 : 0;
    }
}
__device__ __forceinline__ int ld_src(const int* e, int f, int i) {
    int v = f ? e[2 * i] : e[i];
    return iclamp(v, 0, NN - 1);
}
__device__ __forceinline__ int ld_dst(const int* e, int f, int i) {
    int v = f ? e[2 * (NE + i)] : e[NE + i];
    return iclamp(v, 0, NN - 1);
}

// ---------------- decoder MLP layer 1 ----------------
template <typename T>
__global__ __launch_bounds__(256) void k_dec1(const int* __restrict__ dtf,
                                              const T* __restrict__ emb,
                                              const T* __restrict__ Wg1,
                                              const T* __restrict__ bg1,
                                              unsigned short* __restrict__ h) {
    if (dtf[0] != tagof<T>::v) return;
    __shared__ float es[EMBD];
    int m = blockIdx.x, t = threadIdx.x;
    if (t < EMBD) es[t] = ldf(emb, (size_t)m * EMBD + t);
    __syncthreads();
    for (int n = t; n < G1D; n += 256) {
        float acc = ldf(bg1, n);
        for (int k = 0; k < EMBD; k++) acc += es[k] * ldf(Wg1, (size_t)k * G1D + n);
        h[m * G1D + n] = f2bf(fmaxf(acc, 0.f));
    }
}

// ---------------- decoder MLP layer 2 (MFMA) ----------------
template <typename T>
__global__ __launch_bounds__(256) void k_dec2(const int* __restrict__ dtf,
                                              const unsigned short* __restrict__ h,
                                              const T* __restrict__ Wg2,
                                              const T* __restrict__ bg2,
                                              unsigned short* __restrict__ x) {
    if (dtf[0] != tagof<T>::v) return;
    int wid = threadIdx.x >> 6, lane = threadIdx.x & 63;
    int q = lane >> 4, l16 = lane & 15;
    int n = blockIdx.x * 64 + wid * 16 + l16;
    float4v acc[7];
    for (int mt = 0; mt < 7; mt++) for (int i = 0; i < 4; i++) acc[mt][i] = 0.f;
    for (int kt = 0; kt < 16; kt++) {
        int k0 = kt * 32 + q * 8;
        short8 bf;
        for (int j = 0; j < 8; j++) bf[j] = (short)ldbf(Wg2, (size_t)(k0 + j) * G2D + n);
        for (int mt = 0; mt < 7; mt++) {
            int row = mt * 16 + l16;
            short8 af;
            if (row < NGR) {
                af = *(const short8*)(h + row * G1D + k0);
            } else {
                for (int j = 0; j < 8; j++) af[j] = 0;
            }
            acc[mt] = MFMA(af, bf, acc[mt]);
        }
    }
    float bias = ldf(bg2, n);
    for (int mt = 0; mt < 7; mt++) {
        for (int i = 0; i < 4; i++) {
            int m = mt * 16 + q * 4 + i;
            if (m < NGR) x[(size_t)m * G2D + n] = f2bf(acc[mt][i] + bias);
        }
    }
}

// ---------------- CSR build (STRIDE = counters per node slot; 16 = 1/64B line) ----
template <int STRIDE>
__global__ __launch_bounds__(256) void k_zero(int* __restrict__ deg) {
    int i = blockIdx.x * 256 + threadIdx.x;
    if (i < NN) deg[(size_t)i * STRIDE] = 0;
}
template <int STRIDE>
__global__ __launch_bounds__(256) void k_hist(const int* __restrict__ eidx, const int* __restrict__ dtf,
                                              int* __restrict__ deg) {
    int e = blockIdx.x * 256 + threadIdx.x;   // grid exact
    int f = dtf[1];
    atomicAdd(&deg[(size_t)ld_dst(eidx, f, e) * STRIDE], 1);
}
template <int STRIDE>
__global__ __launch_bounds__(256) void k_scan1(const int* __restrict__ deg, int* __restrict__ bsum) {
    __shared__ int r[256];
    int t = threadIdx.x, i0 = blockIdx.x * 512 + 2 * t;
    int e0 = (i0 < NN) ? deg[(size_t)i0 * STRIDE] : 0;
    int e1 = (i0 + 1 < NN) ? deg[(size_t)(i0 + 1) * STRIDE] : 0;
    r[t] = e0 + e1;
    __syncthreads();
    for (int off = 128; off > 0; off >>= 1) {
        if (t < off) r[t] += r[t + off];
        __syncthreads();
    }
    if (t == 0) bsum[blockIdx.x] = r[0];
}
__global__ __launch_bounds__(256) void k_scan2(int* __restrict__ bsum, int nblk) {
    __shared__ int sc[256];
    int t = threadIdx.x;
    int v = (t < nblk) ? bsum[t] : 0;
    sc[t] = v;
    __syncthreads();
    for (int off = 1; off < 256; off <<= 1) {
        int u = (t >= off) ? sc[t - off] : 0;
        __syncthreads();
        sc[t] += u;
        __syncthreads();
    }
    if (t < nblk) bsum[t] = sc[t] - v;   // exclusive
}
template <int STRIDE>
__global__ __launch_bounds__(256) void k_scan3(const int* __restrict__ deg, const int* __restrict__ bsum,
                                               int* __restrict__ ptr, int* __restrict__ cur) {
    __shared__ int sc[256];
    int t = threadIdx.x, i0 = blockIdx.x * 512 + 2 * t;
    int e0 = (i0 < NN) ? deg[(size_t)i0 * STRIDE] : 0;
    int e1 = (i0 + 1 < NN) ? deg[(size_t)(i0 + 1) * STRIDE] : 0;
    int s = e0 + e1;
    sc[t] = s;
    __syncthreads();
    for (int off = 1; off < 256; off <<= 1) {
        int v = (t >= off) ? sc[t - off] : 0;
        __syncthreads();
        sc[t] += v;
        __syncthreads();
    }
    int excl = sc[t] - s;
    int p0 = bsum[blockIdx.x] + excl;
    if (i0 < NN)     { ptr[i0] = p0;          cur[(size_t)i0 * STRIDE] = p0; }
    if (i0 + 1 < NN) { ptr[i0 + 1] = p0 + e0; cur[(size_t)(i0 + 1) * STRIDE] = p0 + e0; }
    if (blockIdx.x == 0 && t == 0) ptr[NN] = NE;
}
// MODE<=1: csr.x stores the Y-ROW BYTE OFFSET (clamped src * DD * 2)
template <int STRIDE>
__global__ __launch_bounds__(256) void k_fill(const int* __restrict__ eidx, const int* __restrict__ dtf,
                                              int* __restrict__ cur, int2* __restrict__ csr) {
    int e = blockIdx.x * 256 + threadIdx.x;   // grid exact
    int f = dtf[1];
    int src = ld_src(eidx, f, e);
    int dst = ld_dst(eidx, f, e);
    int pos = atomicAdd(&cur[(size_t)dst * STRIDE], 1);
    pos = iclamp(pos, 0, NE - 1);
    csr[pos] = make_int2(src * (DD * 2), e);
}

// MODE==2: fused fill+permute. 64B record per CSR slot:
//   shorts [0,16): bf16 edge_attr row   int @byte32: src y-row byte offset   rest: pad
// ea read is COALESCED (thread e reads row e); write is one FULL 64B line.
template <typename T, int STRIDE>
__global__ __launch_bounds__(256) void k_fill2(const int* __restrict__ eidx, const int* __restrict__ dtf,
                                               const T* __restrict__ ea,
                                               int* __restrict__ cur, uint4* __restrict__ rows) {
    if (dtf[0] != tagof<T>::v) return;
    int e = blockIdx.x * 256 + threadIdx.x;   // grid exact
    int f = dtf[1];
    int src = ld_src(eidx, f, e);
    int dst = ld_dst(eidx, f, e);
    float ev[16];
    ld16v(ea + (size_t)e * ECH, ev);
    unsigned int wv[8];
    #pragma unroll
    for (int i = 0; i < 8; i++)
        wv[i] = (unsigned int)f2bf(ev[2 * i]) | ((unsigned int)f2bf(ev[2 * i + 1]) << 16);
    int pos = atomicAdd(&cur[(size_t)dst * STRIDE], 1);
    pos = iclamp(pos, 0, NE - 1);
    uint4* r = rows + (size_t)pos * 4;
    r[0] = make_uint4(wv[0], wv[1], wv[2], wv[3]);
    r[1] = make_uint4(wv[4], wv[5], wv[6], wv[7]);
    r[2] = make_uint4((unsigned int)(src * (DD * 2)), 0u, 0u, 0u);
    r[3] = make_uint4(0u, 0u, 0u, 0u);   // full-line write
}

// ---------------- permute edge_attr into CSR order (MODE==1) ----------------
template <typename T>
__global__ __launch_bounds__(256) void k_eaperm(const int* __restrict__ dtf,
                                                const int2* __restrict__ csr,
                                                const T* __restrict__ ea,
                                                unsigned short* __restrict__ eaP) {
    if (dtf[0] != tagof<T>::v) return;
    int p = blockIdx.x * 256 + threadIdx.x;   // grid exact: NE/256
    int eid = iclamp(csr[p].y, 0, NE - 1);
    float ev[16];
    ld16v(ea + (size_t)eid * ECH, ev);
    unsigned int wv[8];
    for (int i = 0; i < 8; i++)
        wv[i] = (unsigned int)f2bf(ev[2 * i]) | ((unsigned int)f2bf(ev[2 * i + 1]) << 16);
    uint4* op = (uint4*)(eaP + (size_t)p * ECH);
    op[0] = make_uint4(wv[0], wv[1], wv[2], wv[3]);
    op[1] = make_uint4(wv[4], wv[5], wv[6], wv[7]);
}

// ---------------- MFMA edge aggregation, MODE==2 (64B rows, single stream) ----------
// Fragment maps identical to gemm_node (harness-verified):
//   A: row=l16, k=q*8+j   B: k=q*8+j, col=l16   D: row=q*4+i, col=l16
template <typename T>
__global__ __launch_bounds__(256) void k_agg_mfma2(const int* __restrict__ dtf,
                                                   const int* __restrict__ ptr,
                                                   const unsigned short* __restrict__ y,
                                                   const unsigned short* __restrict__ rows,
                                                   const T* __restrict__ mW,
                                                   const T* __restrict__ mb,
                                                   unsigned short* __restrict__ agg) {
    if (dtf[0] != tagof<T>::v) return;
    int nid = blockIdx.x * 4 + (threadIdx.x >> 6);
    int lane = threadIdx.x & 63;
    int q = lane >> 4, l16 = lane & 15;

    short8 bfr[4];
    #pragma unroll
    for (int nt = 0; nt < 4; nt++) {
        short8 b;
        #pragma unroll
        for (int j = 0; j < 8; j++) b[j] = 0;
        if (q < 2) {
            #pragma unroll
            for (int j = 0; j < 8; j++)
                b[j] = (short)ldbf(mW, (size_t)(DD + q * 8 + j) * DD + nt * 16 + l16);
        }
        bfr[nt] = b;
    }
    float mbc[4];
    #pragma unroll
    for (int nt = 0; nt < 4; nt++) mbc[nt] = ldf(mb, nt * 16 + l16);

    int s = iclamp(ptr[nid], 0, NE);
    int e = iclamp(ptr[nid + 1], s, NE);

    float acc[4] = {0.f, 0.f, 0.f, 0.f};
    const float4v z4 = {0.f, 0.f, 0.f, 0.f};

    for (int t = s; t < e; t += 16) {
        short8 af;
        #pragma unroll
        for (int j = 0; j < 8; j++) af[j] = 0;
        int erow = t + l16;
        if (erow < e && q < 2)
            af = *(const short8*)(rows + (size_t)erow * 32 + q * 8);

        int off[4]; bool val[4];
        #pragma unroll
        for (int i = 0; i < 4; i++) {
            int idx = t + q * 4 + i;
            val[i] = idx < e;
            int cidx = idx < e ? idx : (e - 1);
            off[i] = *(const int*)(rows + (size_t)cidx * 32 + 16);   // byte 32 of the row
        }

        #pragma unroll
        for (int nt = 0; nt < 4; nt++) {
            float4v p = MFMA(af, bfr[nt], z4);
            int colb = (nt * 16 + l16) * 2;
            #pragma unroll
            for (int i = 0; i < 4; i++) {
                float yv = bf2f(*(const unsigned short*)((const char*)y + (unsigned int)(off[i] + colb)));
                float z = fmaxf(p[i] + yv + mbc[nt], 0.f);
                acc[nt] += val[i] ? z : 0.f;
            }
        }
    }

    #pragma unroll
    for (int nt = 0; nt < 4; nt++) {
        acc[nt] += __shfl_xor(acc[nt], 16);
        acc[nt] += __shfl_xor(acc[nt], 32);
    }
    float r = (q == 0) ? acc[0] : (q == 1) ? acc[1] : (q == 2) ? acc[2] : acc[3];
    agg[(size_t)nid * DD + lane] = f2bf(r);
}

// ---------------- MFMA edge aggregation, MODE==1 (eaP32 + csr) ----------------
template <typename T>
__global__ __launch_bounds__(256) void k_agg_mfma(const int* __restrict__ dtf,
                                                  const int2* __restrict__ csr,
                                                  const int* __restrict__ ptr,
                                                  const unsigned short* __restrict__ y,
                                                  const unsigned short* __restrict__ eaP,
                                                  const T* __restrict__ mW,
                                                  const T* __restrict__ mb,
                                                  unsigned short* __restrict__ agg) {
    if (dtf[0] != tagof<T>::v) return;
    int nid = blockIdx.x * 4 + (threadIdx.x >> 6);
    int lane = threadIdx.x & 63;
    int q = lane >> 4, l16 = lane & 15;

    short8 bfr[4];
    #pragma unroll
    for (int nt = 0; nt < 4; nt++) {
        short8 b;
        #pragma unroll
        for (int j = 0; j < 8; j++) b[j] = 0;
        if (q < 2) {
            #pragma unroll
            for (int j = 0; j < 8; j++)
                b[j] = (short)ldbf(mW, (size_t)(DD + q * 8 + j) * DD + nt * 16 + l16);
        }
        bfr[nt] = b;
    }
    float mbc[4];
    #pragma unroll
    for (int nt = 0; nt < 4; nt++) mbc[nt] = ldf(mb, nt * 16 + l16);

    int s = iclamp(ptr[nid], 0, NE);
    int e = iclamp(ptr[nid + 1], s, NE);

    float acc[4] = {0.f, 0.f, 0.f, 0.f};
    const float4v z4 = {0.f, 0.f, 0.f, 0.f};

    for (int t = s; t < e; t += 16) {
        short8 af;
        #pragma unroll
        for (int j = 0; j < 8; j++) af[j] = 0;
        int erow = t + l16;
        if (erow < e && q < 2)
            af = *(const short8*)(eaP + (size_t)erow * ECH + q * 8);

        int off[4]; bool val[4];
        #pragma unroll
        for (int i = 0; i < 4; i++) {
            int idx = t + q * 4 + i;
            val[i] = idx < e;
            int cidx = idx < e ? idx : (e - 1);
            off[i] = csr[cidx].x;
        }

        #pragma unroll
        for (int nt = 0; nt < 4; nt++) {
            float4v p = MFMA(af, bfr[nt], z4);
            int colb = (nt * 16 + l16) * 2;
            #pragma unroll
            for (int i = 0; i < 4; i++) {
                float yv = bf2f(*(const unsigned short*)((const char*)y + (unsigned int)(off[i] + colb)));
                float z = fmaxf(p[i] + yv + mbc[nt], 0.f);
                acc[nt] += val[i] ? z : 0.f;
            }
        }
    }

    #pragma unroll
    for (int nt = 0; nt < 4; nt++) {
        acc[nt] += __shfl_xor(acc[nt], 16);
        acc[nt] += __shfl_xor(acc[nt], 32);
    }
    float r = (q == 0) ? acc[0] : (q == 1) ? acc[1] : (q == 2) ? acc[2] : acc[3];
    agg[(size_t)nid * DD + lane] = f2bf(r);
}

// ---------------- scalar edge aggregation (MODE==0 fallback) ----------------
template <typename T>
__global__ __launch_bounds__(256) void k_agg(const int* __restrict__ dtf,
                                             const int2* __restrict__ csr, const int* __restrict__ ptr,
                                             const unsigned short* __restrict__ y,
                                             const T* __restrict__ ea,
                                             const T* __restrict__ mW,
                                             const T* __restrict__ mb,
                                             unsigned short* __restrict__ agg) {
    if (dtf[0] != tagof<T>::v) return;
    int nid = blockIdx.x * 4 + (threadIdx.x >> 6);
    int lane = threadIdx.x & 63;
    float wk[16];
    for (int k = 0; k < 16; k++) wk[k] = ldf(mW, (size_t)(DD + k) * DD + lane);
    float mbv = ldf(mb, lane);
    int s = iclamp(ptr[nid], 0, NE);
    int e = iclamp(ptr[nid + 1], s, NE);
    const char* yl = (const char*)y + (size_t)lane * 2;
    float acc = 0.f;
    int t = s;
    for (; t + 2 <= e; t += 2) {
        int2 p0 = csr[t], p1 = csr[t + 1];
        float y0 = bf2f(*(const unsigned short*)(yl + (unsigned int)p0.x));
        float y1 = bf2f(*(const unsigned short*)(yl + (unsigned int)p1.x));
        float e0[16], e1[16];
        ld16v(ea + (size_t)iclamp(p0.y, 0, NE - 1) * ECH, e0);
        ld16v(ea + (size_t)iclamp(p1.y, 0, NE - 1) * ECH, e1);
        float z0 = mbv + y0, z1 = mbv + y1;
        #pragma unroll
        for (int k = 0; k < 16; k++) { z0 = fmaf(e0[k], wk[k], z0); z1 = fmaf(e1[k], wk[k], z1); }
        acc += fmaxf(z0, 0.f) + fmaxf(z1, 0.f);
    }
    for (; t < e; ++t) {
        int2 p = csr[t];
        float yv = bf2f(*(const unsigned short*)(yl + (unsigned int)p.x));
        float ev[16];
        ld16v(ea + (size_t)iclamp(p.y, 0, NE - 1) * ECH, ev);
        float z = mbv + yv;
        #pragma unroll
        for (int k = 0; k < 16; k++) z = fmaf(ev[k], wk[k], z);
        acc += fmaxf(z, 0.f);
    }
    agg[(size_t)nid * DD + lane] = f2bf(acc);
}

// ---------------- generic skinny MFMA GEMM over node rows ----------------
template <typename T, int KT1, int KT2, int NT, bool RELU, bool HASBIAS>
__global__ __launch_bounds__(256) void gemm_node(const int* __restrict__ dtf,
                                                 const unsigned short* __restrict__ A1,
                                                 const unsigned short* __restrict__ A2,
                                                 const T* __restrict__ W,
                                                 const T* __restrict__ bias,
                                                 unsigned short* __restrict__ out) {
    if (dtf[0] != tagof<T>::v) return;
    constexpr int KT = KT1 + KT2;
    constexpr int N = NT * 16;
    int wid = threadIdx.x >> 6, lane = threadIdx.x & 63;
    int q = lane >> 4, l16 = lane & 15;
    int mt = blockIdx.x * 4 + wid;
    int m0 = mt * 16;
    if (m0 >= NN) return;
    short8 bfr[KT][NT];
    for (int kt = 0; kt < KT; kt++)
        for (int nt = 0; nt < NT; nt++)
            for (int j = 0; j < 8; j++)
                bfr[kt][nt][j] = (short)ldbf(W, (size_t)(kt * 32 + q * 8 + j) * N + nt * 16 + l16);
    float4v acc[NT];
    for (int nt = 0; nt < NT; nt++) for (int i = 0; i < 4; i++) acc[nt][i] = 0.f;

    const unsigned short* a1p = A1 + (size_t)(m0 + l16) * (KT1 * 32) + q * 8;
    for (int kt = 0; kt < KT1; kt++) {
        short8 af = *(const short8*)(a1p + kt * 32);
        for (int nt = 0; nt < NT; nt++) acc[nt] = MFMA(af, bfr[kt][nt], acc[nt]);
    }
    if constexpr (KT2 > 0) {
        const unsigned short* a2p = A2 + (size_t)(m0 + l16) * (KT2 * 32) + q * 8;
        for (int kt = 0; kt < KT2; kt++) {
            short8 af = *(const short8*)(a2p + kt * 32);
            for (int nt = 0; nt < NT; nt++) acc[nt] = MFMA(af, bfr[KT1 + kt][nt], acc[nt]);
        }
    }
    for (int nt = 0; nt < NT; nt++) {
        int n = nt * 16 + l16;
        float b = HASBIAS ? ldf(bias, n) : 0.f;
        for (int i = 0; i < 4; i++) {
            float v = acc[nt][i] + b;
            if (RELU) v = fmaxf(v, 0.f);
            out[(size_t)(m0 + q * 4 + i) * N + n] = f2bf(v);
        }
    }
}

// ---------------- fused node MLP ----------------
template <typename T>
__global__ __launch_bounds__(256) void k_mlp_out(const int* __restrict__ dtf,
                                                 const unsigned short* __restrict__ A,
                                                 const T* __restrict__ nW1,
                                                 const T* __restrict__ nb1,
                                                 const T* __restrict__ nW2,
                                                 const T* __restrict__ nb2,
                                                 T* __restrict__ out) {
    if (dtf[0] != tagof<T>::v) return;
    constexpr int NT = 8, N = 128;
    int wid = threadIdx.x >> 6, lane = threadIdx.x & 63;
    int q = lane >> 4, l16 = lane & 15;
    int mt = blockIdx.x * 4 + wid;
    int m0 = mt * 16;
    if (m0 >= NN) return;
    short8 bfr[2][NT];
    float cb[NT], w2r[NT][3];
    for (int kt = 0; kt < 2; kt++)
        for (int nt = 0; nt < NT; nt++)
            for (int j = 0; j < 8; j++)
                bfr[kt][nt][j] = (short)ldbf(nW1, (size_t)(kt * 32 + q * 8 + j) * N + nt * 16 + l16);
    for (int nt = 0; nt < NT; nt++) {
        int col = nt * 16 + l16;
        cb[nt] = ldf(nb1, col);
        for (int j = 0; j < 3; j++) w2r[nt][j] = ldf(nW2, (size_t)col * 3 + j);
    }
    float4v acc[NT];
    for (int nt = 0; nt < NT; nt++) for (int i = 0; i < 4; i++) acc[nt][i] = 0.f;
    const unsigned short* ap = A + (size_t)(m0 + l16) * DD + q * 8;
    for (int kt = 0; kt < 2; kt++) {
        short8 af = *(const short8*)(ap + kt * 32);
        for (int nt = 0; nt < NT; nt++) acc[nt] = MFMA(af, bfr[kt][nt], acc[nt]);
    }
    float b0 = ldf(nb2, 0), b1 = ldf(nb2, 1), b2 = ldf(nb2, 2);
    for (int i = 0; i < 4; i++) {
        float p0 = 0.f, p1 = 0.f, p2 = 0.f;
        for (int nt = 0; nt < 8; nt++) {
            float v = fmaxf(acc[nt][i] + cb[nt], 0.f);
            p0 += v * w2r[nt][0];
            p1 += v * w2r[nt][1];
            p2 += v * w2r[nt][2];
        }
        for (int m = 1; m < 16; m <<= 1) {
            p0 += __shfl_xor(p0, m);
            p1 += __shfl_xor(p1, m);
            p2 += __shfl_xor(p2, m);
        }
        if (l16 == 0) {
            size_t row = (size_t)(m0 + q * 4 + i) * 3;
            stf(out, row + 0, p0 + b0);
            stf(out, row + 1, p1 + b1);
            stf(out, row + 2, p2 + b2);
        }
    }
}

// ---------------- workspace plan ----------------
struct WSPlan {
    unsigned short *nA, *nB, *nG, *hb, *eaP;
    int2* csr;
    int *deg, *ptr, *cur, *bsum, *dtf;
    size_t used;
};
static WSPlan carve_plan(char* w, int stride, size_t eaBytes, bool needCsr) {
    WSPlan r;
    size_t off = 0;
    auto cv = [&](size_t b) -> char* { char* p = w + off; off = (off + b + 255) & ~(size_t)255; return p; };
    r.nA  = (unsigned short*)cv((size_t)NN * DD * 2);            // 12.8 MB
    r.nB  = (unsigned short*)cv((size_t)NN * DD * 2);            // 12.8 MB
    r.nG  = (unsigned short*)cv((size_t)NN * DD * 2);            // 12.8 MB
    r.csr = needCsr ? (int2*)cv((size_t)NE * 8) : nullptr;       // 12.8 MB (modes 0/1)
    r.hb  = (unsigned short*)cv((size_t)NGR * G1D * 2);          // 0.1 MB
    r.deg = (int*)cv((size_t)NN * stride * 4);
    r.ptr = (int*)cv((size_t)(NN + 1) * 4);
    r.cur = (int*)cv((size_t)NN * stride * 4);
    r.bsum = (int*)cv((size_t)256 * 4);
    r.dtf  = (int*)cv(256);
    r.eaP = eaBytes ? (unsigned short*)cv(eaBytes) : nullptr;
    r.used = off;
    return r;
}

// ---------------- typed pipeline launcher ----------------
// MODE: 2 = fused 64B rows (stride-16 counters), 1 = eaP32 + csr (round-2 verified), 0 = scalar
template <typename T, int MODE>
static void launch_typed(void* const* d_in, void* d_out, hipStream_t stream,
                         const WSPlan& P, const int* eix, int GEMM_BLKS) {
    const T* emb = (const T*)d_in[0];
    const T* ea  = (const T*)d_in[2];
    const T* Wg1 = (const T*)d_in[3];  const T* bg1 = (const T*)d_in[4];
    const T* Wg2 = (const T*)d_in[5];  const T* bg2 = (const T*)d_in[6];
    const T* mW0 = (const T*)d_in[7];  const T* mb0 = (const T*)d_in[8];
    const T* uW0 = (const T*)d_in[9];  const T* ub0 = (const T*)d_in[10];
    const T* mW1 = (const T*)d_in[11]; const T* mb1 = (const T*)d_in[12];
    const T* uW1 = (const T*)d_in[13]; const T* ub1 = (const T*)d_in[14];
    const T* nW1 = (const T*)d_in[15]; const T* nb1 = (const T*)d_in[16];
    const T* nW2 = (const T*)d_in[17]; const T* nb2 = (const T*)d_in[18];
    T* out = (T*)d_out;

    if constexpr (MODE == 2)
        k_fill2<T, 16><<<NE / 256, 256, 0, stream>>>(eix, P.dtf, ea, P.cur, (uint4*)P.eaP);

    k_dec1<T><<<NGR, 256, 0, stream>>>(P.dtf, emb, Wg1, bg1, P.hb);
    k_dec2<T><<<G2D / 64, 256, 0, stream>>>(P.dtf, P.hb, Wg2, bg2, P.nA);

    if constexpr (MODE == 1)
        k_eaperm<T><<<NE / 256, 256, 0, stream>>>(P.dtf, P.csr, ea, P.eaP);

    gemm_node<T, 2, 0, 4, false, false><<<GEMM_BLKS, 256, 0, stream>>>(P.dtf, P.nA, nullptr, mW0, nullptr, P.nB);
    if constexpr (MODE == 2)
        k_agg_mfma2<T><<<NN / 4, 256, 0, stream>>>(P.dtf, P.ptr, P.nB, P.eaP, mW0, mb0, P.nG);
    else if constexpr (MODE == 1)
        k_agg_mfma<T><<<NN / 4, 256, 0, stream>>>(P.dtf, P.csr, P.ptr, P.nB, P.eaP, mW0, mb0, P.nG);
    else
        k_agg<T><<<NN / 4, 256, 0, stream>>>(P.dtf, P.csr, P.ptr, P.nB, ea, mW0, mb0, P.nG);
    gemm_node<T, 2, 2, 4, true, true><<<GEMM_BLKS, 256, 0, stream>>>(P.dtf, P.nA, P.nG, uW0, ub0, P.nB);

    gemm_node<T, 2, 0, 4, false, false><<<GEMM_BLKS, 256, 0, stream>>>(P.dtf, P.nB, nullptr, mW1, nullptr, P.nA);
    if constexpr (MODE == 2)
        k_agg_mfma2<T><<<NN / 4, 256, 0, stream>>>(P.dtf, P.ptr, P.nA, P.eaP, mW1, mb1, P.nG);
    else if constexpr (MODE == 1)
        k_agg_mfma<T><<<NN / 4, 256, 0, stream>>>(P.dtf, P.csr, P.ptr, P.nA, P.eaP, mW1, mb1, P.nG);
    else
        k_agg<T><<<NN / 4, 256, 0, stream>>>(P.dtf, P.csr, P.ptr, P.nA, ea, mW1, mb1, P.nG);
    gemm_node<T, 2, 2, 4, true, true><<<GEMM_BLKS, 256, 0, stream>>>(P.dtf, P.nB, P.nG, uW1, ub1, P.nA);

    k_mlp_out<T><<<GEMM_BLKS, 256, 0, stream>>>(P.dtf, P.nA, nW1, nb1, nW2, nb2, out);
}

extern "C" void kernel_launch(void* const* d_in, const int* in_sizes, int n_in,
                              void* d_out, int out_size, void* d_ws, size_t ws_size,
                              hipStream_t stream) {
    const int* eix = (const int*)d_in[1];
    char* w = (char*)d_ws;
    (void)in_sizes; (void)n_in; (void)out_size;

    // Mode selection by pure size arithmetic (host-constant: graph-safe).
    //   mode 2: ~154 MB  (64B records, padded counters, no csr)
    //   mode 1: ~103.5MB (exact round-2 verified footprint)
    //   mode 0: ~52.5 MB
    WSPlan p2 = carve_plan(w, 16, (size_t)NE * 64, false);
    WSPlan p1 = carve_plan(w, 1, (size_t)NE * ECH * 2, true);
    WSPlan p0 = carve_plan(w, 1, 0, true);
    int mode;
    WSPlan P;
    if (p2.used <= ws_size) { mode = 2; P = p2; }
    else if (p1.used <= ws_size) { mode = 1; P = p1; }
    else { mode = 0; P = p0; }

    const int SCAN_BLKS = (NN + 511) / 512;   // 196
    const int GEMM_BLKS = (NN / 16 + 3) / 4;  // 1563

    k_detect<<<1, 64, 0, stream>>>((const unsigned short*)d_in[0], eix, P.dtf);

    // CSR build (dtype-independent part)
    if (mode == 2) {
        k_zero<16><<<(NN + 255) / 256, 256, 0, stream>>>(P.deg);
        k_hist<16><<<NE / 256, 256, 0, stream>>>(eix, P.dtf, P.deg);
        k_scan1<16><<<SCAN_BLKS, 256, 0, stream>>>(P.deg, P.bsum);
        k_scan2<<<1, 256, 0, stream>>>(P.bsum, SCAN_BLKS);
        k_scan3<16><<<SCAN_BLKS, 256, 0, stream>>>(P.deg, P.bsum, P.ptr, P.cur);
    } else {
        k_zero<1><<<(NN + 255) / 256, 256, 0, stream>>>(P.deg);
        k_hist<1><<<NE / 256, 256, 0, stream>>>(eix, P.dtf, P.deg);
        k_scan1<1><<<SCAN_BLKS, 256, 0, stream>>>(P.deg, P.bsum);
        k_scan2<<<1, 256, 0, stream>>>(P.bsum, SCAN_BLKS);
        k_scan3<1><<<SCAN_BLKS, 256, 0, stream>>>(P.deg, P.bsum, P.ptr, P.cur);
        k_fill<1><<<NE / 256, 256, 0, stream>>>(eix, P.dtf, P.cur, P.csr);
    }

    // launch both dtype variants; the wrong one early-exits on dtf[0]
    if (mode == 2) {
        launch_typed<float, 2>(d_in, d_out, stream, P, eix, GEMM_BLKS);
        launch_typed<unsigned short, 2>(d_in, d_out, stream, P, eix, GEMM_BLKS);
    } else if (mode == 1) {
        launch_typed<float, 1>(d_in, d_out, stream, P, eix, GEMM_BLKS);
        launch_typed<unsigned short, 1>(d_in, d_out, stream, P, eix, GEMM_BLKS);
    } else {
        launch_typed<float, 0>(d_in, d_out, stream, P, eix, GEMM_BLKS);
        launch_typed<unsigned short, 0>(d_in, d_out, stream, P, eix, GEMM_BLKS);
    }
}

// Round 5
// 802.312 us; speedup vs baseline: 1.2485x; 1.0119x over previous
//
#include <hip/hip_runtime.h>

// Problem constants (from reference)
#define NN   100000      // nodes
#define NE   1600000     // edges
#define DD   64          // node feature dim
#define ECH  16          // edge channels
#define EMBD 128
#define G1D  512
#define G2D  64000
#define NGR  100         // graphs
#define NM1D 128
// counter stride for mode-2 CSR build: 4 ints (16B) apart.
//   stride 1  (400KB): L2-resident but 256 atomics/line serialize (round-2: slow fill)
//   stride 16 (6.4MB): no serialization but > 4MiB per-XCD L2 -> 51MB atomic writeback (round-4)
//   stride 4  (1.6MB): L2-resident AND only 4 counters/line
#define CSTR 4

typedef __attribute__((ext_vector_type(8))) short short8;
typedef __attribute__((ext_vector_type(4))) float float4v;

__device__ __forceinline__ float bf2f(unsigned short u) {
    union { unsigned int i; float f; } v; v.i = ((unsigned int)u) << 16; return v.f;
}
__device__ __forceinline__ unsigned short f2bf(float f) {
    union { unsigned int i; float f; } v; v.f = f;
    unsigned int u = v.i;
    return (unsigned short)((u + 0x7fffu + ((u >> 16) & 1u)) >> 16);
}
__device__ __forceinline__ float blo(unsigned int d) {
    union { unsigned int i; float f; } v; v.i = d << 16; return v.f;
}
__device__ __forceinline__ float bhi(unsigned int d) {
    union { unsigned int i; float f; } v; v.i = d & 0xffff0000u; return v.f;
}
__device__ __forceinline__ int iclamp(int v, int lo, int hi) {
    return v < lo ? lo : (v > hi ? hi : v);
}

// ---- dtype-generic accessors (T = float or unsigned short[bf16]) ----
__device__ __forceinline__ float ldf(const float* p, size_t i) { return p[i]; }
__device__ __forceinline__ float ldf(const unsigned short* p, size_t i) { return bf2f(p[i]); }
__device__ __forceinline__ unsigned short ldbf(const float* p, size_t i) { return f2bf(p[i]); }
__device__ __forceinline__ unsigned short ldbf(const unsigned short* p, size_t i) { return p[i]; }
__device__ __forceinline__ void stf(float* p, size_t i, float v) { p[i] = v; }
__device__ __forceinline__ void stf(unsigned short* p, size_t i, float v) { p[i] = f2bf(v); }
__device__ __forceinline__ void ld16v(const float* p, float* o) {
    const float4* q = (const float4*)p;
    float4 a = q[0], b = q[1], c = q[2], d = q[3];
    o[0]=a.x; o[1]=a.y; o[2]=a.z; o[3]=a.w;
    o[4]=b.x; o[5]=b.y; o[6]=b.z; o[7]=b.w;
    o[8]=c.x; o[9]=c.y; o[10]=c.z; o[11]=c.w;
    o[12]=d.x; o[13]=d.y; o[14]=d.z; o[15]=d.w;
}
__device__ __forceinline__ void ld16v(const unsigned short* p, float* o) {
    const uint4* q = (const uint4*)p;
    uint4 a = q[0], b = q[1];
    o[0]=blo(a.x); o[1]=bhi(a.x); o[2]=blo(a.y); o[3]=bhi(a.y);
    o[4]=blo(a.z); o[5]=bhi(a.z); o[6]=blo(a.w); o[7]=bhi(a.w);
    o[8]=blo(b.x); o[9]=bhi(b.x); o[10]=blo(b.y); o[11]=bhi(b.y);
    o[12]=blo(b.z); o[13]=bhi(b.z); o[14]=blo(b.w); o[15]=bhi(b.w);
}
template <typename T> struct tagof;
template <> struct tagof<float> { static constexpr int v = 0; };
template <> struct tagof<unsigned short> { static constexpr int v = 1; };

#define MFMA(a, b, c) __builtin_amdgcn_mfma_f32_16x16x32_bf16((a), (b), (c), 0, 0, 0)

// ---------------- runtime dtype detection (parallel, 1 wave) ----------------
__global__ __launch_bounds__(64) void k_detect(const unsigned short* __restrict__ embu,
                                               const int* __restrict__ eidx,
                                               int* __restrict__ dtf) {
    int lane = threadIdx.x;
    int sane = 0;
    for (int i = lane; i < 512; i += 64) {
        unsigned short x = embu[i];
        int e = (x >> 7) & 0xFF;
        if (x == 0 || (e >= 97 && e <= 157)) sane++;
    }
    for (int m = 32; m >= 1; m >>= 1) sane += __shfl_xor(sane, m);
    int oddNZ = 0, evenNZ = 0;
    for (int i = lane; i < 256; i += 64) {
        if (eidx[2 * i + 1] != 0) oddNZ = 1;
        if (eidx[2 * i] != 0) evenNZ = 1;
    }
    unsigned long long bo = __ballot(oddNZ);
    unsigned long long be = __ballot(evenNZ);
    if (lane == 0) {
        dtf[0] = (sane >= 461) ? 1 : 0;
        dtf[1] = (bo == 0ULL && be != 0ULL) ? 1 : 0;
    }
}
__device__ __forceinline__ int ld_src(const int* e, int f, int i) {
    int v = f ? e[2 * i] : e[i];
    return iclamp(v, 0, NN - 1);
}
__device__ __forceinline__ int ld_dst(const int* e, int f, int i) {
    int v = f ? e[2 * (NE + i)] : e[NE + i];
    return iclamp(v, 0, NN - 1);
}

// ---------------- decoder MLP layer 1 ----------------
template <typename T>
__global__ __launch_bounds__(256) void k_dec1(const int* __restrict__ dtf,
                                              const T* __restrict__ emb,
                                              const T* __restrict__ Wg1,
                                              const T* __restrict__ bg1,
                                              unsigned short* __restrict__ h) {
    if (dtf[0] != tagof<T>::v) return;
    __shared__ float es[EMBD];
    int m = blockIdx.x, t = threadIdx.x;
    if (t < EMBD) es[t] = ldf(emb, (size_t)m * EMBD + t);
    __syncthreads();
    for (int n = t; n < G1D; n += 256) {
        float acc = ldf(bg1, n);
        for (int k = 0; k < EMBD; k++) acc += es[k] * ldf(Wg1, (size_t)k * G1D + n);
        h[m * G1D + n] = f2bf(fmaxf(acc, 0.f));
    }
}

// ---------------- decoder MLP layer 2 (MFMA) ----------------
template <typename T>
__global__ __launch_bounds__(256) void k_dec2(const int* __restrict__ dtf,
                                              const unsigned short* __restrict__ h,
                                              const T* __restrict__ Wg2,
                                              const T* __restrict__ bg2,
                                              unsigned short* __restrict__ x) {
    if (dtf[0] != tagof<T>::v) return;
    int wid = threadIdx.x >> 6, lane = threadIdx.x & 63;
    int q = lane >> 4, l16 = lane & 15;
    int n = blockIdx.x * 64 + wid * 16 + l16;
    float4v acc[7];
    for (int mt = 0; mt < 7; mt++) for (int i = 0; i < 4; i++) acc[mt][i] = 0.f;
    for (int kt = 0; kt < 16; kt++) {
        int k0 = kt * 32 + q * 8;
        short8 bf;
        for (int j = 0; j < 8; j++) bf[j] = (short)ldbf(Wg2, (size_t)(k0 + j) * G2D + n);
        for (int mt = 0; mt < 7; mt++) {
            int row = mt * 16 + l16;
            short8 af;
            if (row < NGR) {
                af = *(const short8*)(h + row * G1D + k0);
            } else {
                for (int j = 0; j < 8; j++) af[j] = 0;
            }
            acc[mt] = MFMA(af, bf, acc[mt]);
        }
    }
    float bias = ldf(bg2, n);
    for (int mt = 0; mt < 7; mt++) {
        for (int i = 0; i < 4; i++) {
            int m = mt * 16 + q * 4 + i;
            if (m < NGR) x[(size_t)m * G2D + n] = f2bf(acc[mt][i] + bias);
        }
    }
}

// ---------------- CSR build (STRIDE = ints between counters) ----------------
template <int STRIDE>
__global__ __launch_bounds__(256) void k_zero(int* __restrict__ deg) {
    int i = blockIdx.x * 256 + threadIdx.x;
    if (i < NN) deg[(size_t)i * STRIDE] = 0;
}
template <int STRIDE>
__global__ __launch_bounds__(256) void k_hist(const int* __restrict__ eidx, const int* __restrict__ dtf,
                                              int* __restrict__ deg) {
    int e = blockIdx.x * 256 + threadIdx.x;   // grid exact
    int f = dtf[1];
    atomicAdd(&deg[(size_t)ld_dst(eidx, f, e) * STRIDE], 1);
}
template <int STRIDE>
__global__ __launch_bounds__(256) void k_scan1(const int* __restrict__ deg, int* __restrict__ bsum) {
    __shared__ int r[256];
    int t = threadIdx.x, i0 = blockIdx.x * 512 + 2 * t;
    int e0 = (i0 < NN) ? deg[(size_t)i0 * STRIDE] : 0;
    int e1 = (i0 + 1 < NN) ? deg[(size_t)(i0 + 1) * STRIDE] : 0;
    r[t] = e0 + e1;
    __syncthreads();
    for (int off = 128; off > 0; off >>= 1) {
        if (t < off) r[t] += r[t + off];
        __syncthreads();
    }
    if (t == 0) bsum[blockIdx.x] = r[0];
}
__global__ __launch_bounds__(256) void k_scan2(int* __restrict__ bsum, int nblk) {
    __shared__ int sc[256];
    int t = threadIdx.x;
    int v = (t < nblk) ? bsum[t] : 0;
    sc[t] = v;
    __syncthreads();
    for (int off = 1; off < 256; off <<= 1) {
        int u = (t >= off) ? sc[t - off] : 0;
        __syncthreads();
        sc[t] += u;
        __syncthreads();
    }
    if (t < nblk) bsum[t] = sc[t] - v;   // exclusive
}
template <int STRIDE>
__global__ __launch_bounds__(256) void k_scan3(const int* __restrict__ deg, const int* __restrict__ bsum,
                                               int* __restrict__ ptr, int* __restrict__ cur) {
    __shared__ int sc[256];
    int t = threadIdx.x, i0 = blockIdx.x * 512 + 2 * t;
    int e0 = (i0 < NN) ? deg[(size_t)i0 * STRIDE] : 0;
    int e1 = (i0 + 1 < NN) ? deg[(size_t)(i0 + 1) * STRIDE] : 0;
    int s = e0 + e1;
    sc[t] = s;
    __syncthreads();
    for (int off = 1; off < 256; off <<= 1) {
        int v = (t >= off) ? sc[t - off] : 0;
        __syncthreads();
        sc[t] += v;
        __syncthreads();
    }
    int excl = sc[t] - s;
    int p0 = bsum[blockIdx.x] + excl;
    if (i0 < NN)     { ptr[i0] = p0;          cur[(size_t)i0 * STRIDE] = p0; }
    if (i0 + 1 < NN) { ptr[i0 + 1] = p0 + e0; cur[(size_t)(i0 + 1) * STRIDE] = p0 + e0; }
    if (blockIdx.x == 0 && t == 0) ptr[NN] = NE;
}
// MODE<=1: csr.x stores the Y-ROW BYTE OFFSET (clamped src * DD * 2)
template <int STRIDE>
__global__ __launch_bounds__(256) void k_fill(const int* __restrict__ eidx, const int* __restrict__ dtf,
                                              int* __restrict__ cur, int2* __restrict__ csr) {
    int e = blockIdx.x * 256 + threadIdx.x;   // grid exact
    int f = dtf[1];
    int src = ld_src(eidx, f, e);
    int dst = ld_dst(eidx, f, e);
    int pos = atomicAdd(&cur[(size_t)dst * STRIDE], 1);
    pos = iclamp(pos, 0, NE - 1);
    csr[pos] = make_int2(src * (DD * 2), e);
}

// MODE==2: fused fill+permute. 64B record per CSR slot:
//   shorts [0,16): bf16 edge_attr row   int @byte32: src y-row byte offset   rest: pad
// ea read is COALESCED (thread e reads row e); write is one FULL 64B line.
template <typename T, int STRIDE>
__global__ __launch_bounds__(256) void k_fill2(const int* __restrict__ eidx, const int* __restrict__ dtf,
                                               const T* __restrict__ ea,
                                               int* __restrict__ cur, uint4* __restrict__ rows) {
    if (dtf[0] != tagof<T>::v) return;
    int e = blockIdx.x * 256 + threadIdx.x;   // grid exact
    int f = dtf[1];
    int src = ld_src(eidx, f, e);
    int dst = ld_dst(eidx, f, e);
    float ev[16];
    ld16v(ea + (size_t)e * ECH, ev);
    unsigned int wv[8];
    #pragma unroll
    for (int i = 0; i < 8; i++)
        wv[i] = (unsigned int)f2bf(ev[2 * i]) | ((unsigned int)f2bf(ev[2 * i + 1]) << 16);
    int pos = atomicAdd(&cur[(size_t)dst * STRIDE], 1);
    pos = iclamp(pos, 0, NE - 1);
    uint4* r = rows + (size_t)pos * 4;
    r[0] = make_uint4(wv[0], wv[1], wv[2], wv[3]);
    r[1] = make_uint4(wv[4], wv[5], wv[6], wv[7]);
    r[2] = make_uint4((unsigned int)(src * (DD * 2)), 0u, 0u, 0u);
    r[3] = make_uint4(0u, 0u, 0u, 0u);   // full-line write
}

// ---------------- permute edge_attr into CSR order (MODE==1) ----------------
template <typename T>
__global__ __launch_bounds__(256) void k_eaperm(const int* __restrict__ dtf,
                                                const int2* __restrict__ csr,
                                                const T* __restrict__ ea,
                                                unsigned short* __restrict__ eaP) {
    if (dtf[0] != tagof<T>::v) return;
    int p = blockIdx.x * 256 + threadIdx.x;   // grid exact: NE/256
    int eid = iclamp(csr[p].y, 0, NE - 1);
    float ev[16];
    ld16v(ea + (size_t)eid * ECH, ev);
    unsigned int wv[8];
    for (int i = 0; i < 8; i++)
        wv[i] = (unsigned int)f2bf(ev[2 * i]) | ((unsigned int)f2bf(ev[2 * i + 1]) << 16);
    uint4* op = (uint4*)(eaP + (size_t)p * ECH);
    op[0] = make_uint4(wv[0], wv[1], wv[2], wv[3]);
    op[1] = make_uint4(wv[4], wv[5], wv[6], wv[7]);
}

// ---------------- MFMA edge aggregation, MODE==2 (64B rows, single stream) ----------
// Fragment maps identical to gemm_node (harness-verified):
//   A: row=l16, k=q*8+j   B: k=q*8+j, col=l16   D: row=q*4+i, col=l16
template <typename T>
__global__ __launch_bounds__(256) void k_agg_mfma2(const int* __restrict__ dtf,
                                                   const int* __restrict__ ptr,
                                                   const unsigned short* __restrict__ y,
                                                   const unsigned short* __restrict__ rows,
                                                   const T* __restrict__ mW,
                                                   const T* __restrict__ mb,
                                                   unsigned short* __restrict__ agg) {
    if (dtf[0] != tagof<T>::v) return;
    int nid = blockIdx.x * 4 + (threadIdx.x >> 6);
    int lane = threadIdx.x & 63;
    int q = lane >> 4, l16 = lane & 15;

    short8 bfr[4];
    #pragma unroll
    for (int nt = 0; nt < 4; nt++) {
        short8 b;
        #pragma unroll
        for (int j = 0; j < 8; j++) b[j] = 0;
        if (q < 2) {
            #pragma unroll
            for (int j = 0; j < 8; j++)
                b[j] = (short)ldbf(mW, (size_t)(DD + q * 8 + j) * DD + nt * 16 + l16);
        }
        bfr[nt] = b;
    }
    float mbc[4];
    #pragma unroll
    for (int nt = 0; nt < 4; nt++) mbc[nt] = ldf(mb, nt * 16 + l16);

    int s = iclamp(ptr[nid], 0, NE);
    int e = iclamp(ptr[nid + 1], s, NE);

    float acc[4] = {0.f, 0.f, 0.f, 0.f};
    const float4v z4 = {0.f, 0.f, 0.f, 0.f};

    for (int t = s; t < e; t += 16) {
        short8 af;
        #pragma unroll
        for (int j = 0; j < 8; j++) af[j] = 0;
        int erow = t + l16;
        if (erow < e && q < 2)
            af = *(const short8*)(rows + (size_t)erow * 32 + q * 8);

        int off[4]; bool val[4];
        #pragma unroll
        for (int i = 0; i < 4; i++) {
            int idx = t + q * 4 + i;
            val[i] = idx < e;
            int cidx = idx < e ? idx : (e - 1);
            off[i] = *(const int*)(rows + (size_t)cidx * 32 + 16);   // byte 32 of the row
        }

        #pragma unroll
        for (int nt = 0; nt < 4; nt++) {
            float4v p = MFMA(af, bfr[nt], z4);
            int colb = (nt * 16 + l16) * 2;
            #pragma unroll
            for (int i = 0; i < 4; i++) {
                float yv = bf2f(*(const unsigned short*)((const char*)y + (unsigned int)(off[i] + colb)));
                float z = fmaxf(p[i] + yv + mbc[nt], 0.f);
                acc[nt] += val[i] ? z : 0.f;
            }
        }
    }

    #pragma unroll
    for (int nt = 0; nt < 4; nt++) {
        acc[nt] += __shfl_xor(acc[nt], 16);
        acc[nt] += __shfl_xor(acc[nt], 32);
    }
    float r = (q == 0) ? acc[0] : (q == 1) ? acc[1] : (q == 2) ? acc[2] : acc[3];
    agg[(size_t)nid * DD + lane] = f2bf(r);
}

// ---------------- MFMA edge aggregation, MODE==1 (eaP32 + csr) ----------------
template <typename T>
__global__ __launch_bounds__(256) void k_agg_mfma(const int* __restrict__ dtf,
                                                  const int2* __restrict__ csr,
                                                  const int* __restrict__ ptr,
                                                  const unsigned short* __restrict__ y,
                                                  const unsigned short* __restrict__ eaP,
                                                  const T* __restrict__ mW,
                                                  const T* __restrict__ mb,
                                                  unsigned short* __restrict__ agg) {
    if (dtf[0] != tagof<T>::v) return;
    int nid = blockIdx.x * 4 + (threadIdx.x >> 6);
    int lane = threadIdx.x & 63;
    int q = lane >> 4, l16 = lane & 15;

    short8 bfr[4];
    #pragma unroll
    for (int nt = 0; nt < 4; nt++) {
        short8 b;
        #pragma unroll
        for (int j = 0; j < 8; j++) b[j] = 0;
        if (q < 2) {
            #pragma unroll
            for (int j = 0; j < 8; j++)
                b[j] = (short)ldbf(mW, (size_t)(DD + q * 8 + j) * DD + nt * 16 + l16);
        }
        bfr[nt] = b;
    }
    float mbc[4];
    #pragma unroll
    for (int nt = 0; nt < 4; nt++) mbc[nt] = ldf(mb, nt * 16 + l16);

    int s = iclamp(ptr[nid], 0, NE);
    int e = iclamp(ptr[nid + 1], s, NE);

    float acc[4] = {0.f, 0.f, 0.f, 0.f};
    const float4v z4 = {0.f, 0.f, 0.f, 0.f};

    for (int t = s; t < e; t += 16) {
        short8 af;
        #pragma unroll
        for (int j = 0; j < 8; j++) af[j] = 0;
        int erow = t + l16;
        if (erow < e && q < 2)
            af = *(const short8*)(eaP + (size_t)erow * ECH + q * 8);

        int off[4]; bool val[4];
        #pragma unroll
        for (int i = 0; i < 4; i++) {
            int idx = t + q * 4 + i;
            val[i] = idx < e;
            int cidx = idx < e ? idx : (e - 1);
            off[i] = csr[cidx].x;
        }

        #pragma unroll
        for (int nt = 0; nt < 4; nt++) {
            float4v p = MFMA(af, bfr[nt], z4);
            int colb = (nt * 16 + l16) * 2;
            #pragma unroll
            for (int i = 0; i < 4; i++) {
                float yv = bf2f(*(const unsigned short*)((const char*)y + (unsigned int)(off[i] + colb)));
                float z = fmaxf(p[i] + yv + mbc[nt], 0.f);
                acc[nt] += val[i] ? z : 0.f;
            }
        }
    }

    #pragma unroll
    for (int nt = 0; nt < 4; nt++) {
        acc[nt] += __shfl_xor(acc[nt], 16);
        acc[nt] += __shfl_xor(acc[nt], 32);
    }
    float r = (q == 0) ? acc[0] : (q == 1) ? acc[1] : (q == 2) ? acc[2] : acc[3];
    agg[(size_t)nid * DD + lane] = f2bf(r);
}

// ---------------- scalar edge aggregation (MODE==0 fallback) ----------------
template <typename T>
__global__ __launch_bounds__(256) void k_agg(const int* __restrict__ dtf,
                                             const int2* __restrict__ csr, const int* __restrict__ ptr,
                                             const unsigned short* __restrict__ y,
                                             const T* __restrict__ ea,
                                             const T* __restrict__ mW,
                                             const T* __restrict__ mb,
                                             unsigned short* __restrict__ agg) {
    if (dtf[0] != tagof<T>::v) return;
    int nid = blockIdx.x * 4 + (threadIdx.x >> 6);
    int lane = threadIdx.x & 63;
    float wk[16];
    for (int k = 0; k < 16; k++) wk[k] = ldf(mW, (size_t)(DD + k) * DD + lane);
    float mbv = ldf(mb, lane);
    int s = iclamp(ptr[nid], 0, NE);
    int e = iclamp(ptr[nid + 1], s, NE);
    const char* yl = (const char*)y + (size_t)lane * 2;
    float acc = 0.f;
    int t = s;
    for (; t + 2 <= e; t += 2) {
        int2 p0 = csr[t], p1 = csr[t + 1];
        float y0 = bf2f(*(const unsigned short*)(yl + (unsigned int)p0.x));
        float y1 = bf2f(*(const unsigned short*)(yl + (unsigned int)p1.x));
        float e0[16], e1[16];
        ld16v(ea + (size_t)iclamp(p0.y, 0, NE - 1) * ECH, e0);
        ld16v(ea + (size_t)iclamp(p1.y, 0, NE - 1) * ECH, e1);
        float z0 = mbv + y0, z1 = mbv + y1;
        #pragma unroll
        for (int k = 0; k < 16; k++) { z0 = fmaf(e0[k], wk[k], z0); z1 = fmaf(e1[k], wk[k], z1); }
        acc += fmaxf(z0, 0.f) + fmaxf(z1, 0.f);
    }
    for (; t < e; ++t) {
        int2 p = csr[t];
        float yv = bf2f(*(const unsigned short*)(yl + (unsigned int)p.x));
        float ev[16];
        ld16v(ea + (size_t)iclamp(p.y, 0, NE - 1) * ECH, ev);
        float z = mbv + yv;
        #pragma unroll
        for (int k = 0; k < 16; k++) z = fmaf(ev[k], wk[k], z);
        acc += fmaxf(z, 0.f);
    }
    agg[(size_t)nid * DD + lane] = f2bf(acc);
}

// ---------------- generic skinny MFMA GEMM over node rows ----------------
template <typename T, int KT1, int KT2, int NT, bool RELU, bool HASBIAS>
__global__ __launch_bounds__(256) void gemm_node(const int* __restrict__ dtf,
                                                 const unsigned short* __restrict__ A1,
                                                 const unsigned short* __restrict__ A2,
                                                 const T* __restrict__ W,
                                                 const T* __restrict__ bias,
                                                 unsigned short* __restrict__ out) {
    if (dtf[0] != tagof<T>::v) return;
    constexpr int KT = KT1 + KT2;
    constexpr int N = NT * 16;
    int wid = threadIdx.x >> 6, lane = threadIdx.x & 63;
    int q = lane >> 4, l16 = lane & 15;
    int mt = blockIdx.x * 4 + wid;
    int m0 = mt * 16;
    if (m0 >= NN) return;
    short8 bfr[KT][NT];
    for (int kt = 0; kt < KT; kt++)
        for (int nt = 0; nt < NT; nt++)
            for (int j = 0; j < 8; j++)
                bfr[kt][nt][j] = (short)ldbf(W, (size_t)(kt * 32 + q * 8 + j) * N + nt * 16 + l16);
    float4v acc[NT];
    for (int nt = 0; nt < NT; nt++) for (int i = 0; i < 4; i++) acc[nt][i] = 0.f;

    const unsigned short* a1p = A1 + (size_t)(m0 + l16) * (KT1 * 32) + q * 8;
    for (int kt = 0; kt < KT1; kt++) {
        short8 af = *(const short8*)(a1p + kt * 32);
        for (int nt = 0; nt < NT; nt++) acc[nt] = MFMA(af, bfr[kt][nt], acc[nt]);
    }
    if constexpr (KT2 > 0) {
        const unsigned short* a2p = A2 + (size_t)(m0 + l16) * (KT2 * 32) + q * 8;
        for (int kt = 0; kt < KT2; kt++) {
            short8 af = *(const short8*)(a2p + kt * 32);
            for (int nt = 0; nt < NT; nt++) acc[nt] = MFMA(af, bfr[KT1 + kt][nt], acc[nt]);
        }
    }
    for (int nt = 0; nt < NT; nt++) {
        int n = nt * 16 + l16;
        float b = HASBIAS ? ldf(bias, n) : 0.f;
        for (int i = 0; i < 4; i++) {
            float v = acc[nt][i] + b;
            if (RELU) v = fmaxf(v, 0.f);
            out[(size_t)(m0 + q * 4 + i) * N + n] = f2bf(v);
        }
    }
}

// ---------------- fused node MLP ----------------
template <typename T>
__global__ __launch_bounds__(256) void k_mlp_out(const int* __restrict__ dtf,
                                                 const unsigned short* __restrict__ A,
                                                 const T* __restrict__ nW1,
                                                 const T* __restrict__ nb1,
                                                 const T* __restrict__ nW2,
                                                 const T* __restrict__ nb2,
                                                 T* __restrict__ out) {
    if (dtf[0] != tagof<T>::v) return;
    constexpr int NT = 8, N = 128;
    int wid = threadIdx.x >> 6, lane = threadIdx.x & 63;
    int q = lane >> 4, l16 = lane & 15;
    int mt = blockIdx.x * 4 + wid;
    int m0 = mt * 16;
    if (m0 >= NN) return;
    short8 bfr[2][NT];
    float cb[NT], w2r[NT][3];
    for (int kt = 0; kt < 2; kt++)
        for (int nt = 0; nt < NT; nt++)
            for (int j = 0; j < 8; j++)
                bfr[kt][nt][j] = (short)ldbf(nW1, (size_t)(kt * 32 + q * 8 + j) * N + nt * 16 + l16);
    for (int nt = 0; nt < NT; nt++) {
        int col = nt * 16 + l16;
        cb[nt] = ldf(nb1, col);
        for (int j = 0; j < 3; j++) w2r[nt][j] = ldf(nW2, (size_t)col * 3 + j);
    }
    float4v acc[NT];
    for (int nt = 0; nt < NT; nt++) for (int i = 0; i < 4; i++) acc[nt][i] = 0.f;
    const unsigned short* ap = A + (size_t)(m0 + l16) * DD + q * 8;
    for (int kt = 0; kt < 2; kt++) {
        short8 af = *(const short8*)(ap + kt * 32);
        for (int nt = 0; nt < NT; nt++) acc[nt] = MFMA(af, bfr[kt][nt], acc[nt]);
    }
    float b0 = ldf(nb2, 0), b1 = ldf(nb2, 1), b2 = ldf(nb2, 2);
    for (int i = 0; i < 4; i++) {
        float p0 = 0.f, p1 = 0.f, p2 = 0.f;
        for (int nt = 0; nt < 8; nt++) {
            float v = fmaxf(acc[nt][i] + cb[nt], 0.f);
            p0 += v * w2r[nt][0];
            p1 += v * w2r[nt][1];
            p2 += v * w2r[nt][2];
        }
        for (int m = 1; m < 16; m <<= 1) {
            p0 += __shfl_xor(p0, m);
            p1 += __shfl_xor(p1, m);
            p2 += __shfl_xor(p2, m);
        }
        if (l16 == 0) {
            size_t row = (size_t)(m0 + q * 4 + i) * 3;
            stf(out, row + 0, p0 + b0);
            stf(out, row + 1, p1 + b1);
            stf(out, row + 2, p2 + b2);
        }
    }
}

// ---------------- workspace plan ----------------
struct WSPlan {
    unsigned short *nA, *nB, *nG, *hb, *eaP;
    int2* csr;
    int *deg, *ptr, *cur, *bsum, *dtf;
    size_t used;
};
static WSPlan carve_plan(char* w, int stride, size_t eaBytes, bool needCsr) {
    WSPlan r;
    size_t off = 0;
    auto cv = [&](size_t b) -> char* { char* p = w + off; off = (off + b + 255) & ~(size_t)255; return p; };
    r.nA  = (unsigned short*)cv((size_t)NN * DD * 2);            // 12.8 MB
    r.nB  = (unsigned short*)cv((size_t)NN * DD * 2);            // 12.8 MB
    r.nG  = (unsigned short*)cv((size_t)NN * DD * 2);            // 12.8 MB
    r.csr = needCsr ? (int2*)cv((size_t)NE * 8) : nullptr;       // 12.8 MB (modes 0/1)
    r.hb  = (unsigned short*)cv((size_t)NGR * G1D * 2);          // 0.1 MB
    r.deg = (int*)cv((size_t)NN * stride * 4);
    r.ptr = (int*)cv((size_t)(NN + 1) * 4);
    r.cur = (int*)cv((size_t)NN * stride * 4);
    r.bsum = (int*)cv((size_t)256 * 4);
    r.dtf  = (int*)cv(256);
    r.eaP = eaBytes ? (unsigned short*)cv(eaBytes) : nullptr;
    r.used = off;
    return r;
}

// ---------------- typed pipeline launcher ----------------
// MODE: 2 = fused 64B rows (stride-CSTR counters), 1 = eaP32 + csr, 0 = scalar
template <typename T, int MODE>
static void launch_typed(void* const* d_in, void* d_out, hipStream_t stream,
                         const WSPlan& P, const int* eix, int GEMM_BLKS) {
    const T* emb = (const T*)d_in[0];
    const T* ea  = (const T*)d_in[2];
    const T* Wg1 = (const T*)d_in[3];  const T* bg1 = (const T*)d_in[4];
    const T* Wg2 = (const T*)d_in[5];  const T* bg2 = (const T*)d_in[6];
    const T* mW0 = (const T*)d_in[7];  const T* mb0 = (const T*)d_in[8];
    const T* uW0 = (const T*)d_in[9];  const T* ub0 = (const T*)d_in[10];
    const T* mW1 = (const T*)d_in[11]; const T* mb1 = (const T*)d_in[12];
    const T* uW1 = (const T*)d_in[13]; const T* ub1 = (const T*)d_in[14];
    const T* nW1 = (const T*)d_in[15]; const T* nb1 = (const T*)d_in[16];
    const T* nW2 = (const T*)d_in[17]; const T* nb2 = (const T*)d_in[18];
    T* out = (T*)d_out;

    if constexpr (MODE == 2)
        k_fill2<T, CSTR><<<NE / 256, 256, 0, stream>>>(eix, P.dtf, ea, P.cur, (uint4*)P.eaP);

    k_dec1<T><<<NGR, 256, 0, stream>>>(P.dtf, emb, Wg1, bg1, P.hb);
    k_dec2<T><<<G2D / 64, 256, 0, stream>>>(P.dtf, P.hb, Wg2, bg2, P.nA);

    if constexpr (MODE == 1)
        k_eaperm<T><<<NE / 256, 256, 0, stream>>>(P.dtf, P.csr, ea, P.eaP);

    gemm_node<T, 2, 0, 4, false, false><<<GEMM_BLKS, 256, 0, stream>>>(P.dtf, P.nA, nullptr, mW0, nullptr, P.nB);
    if constexpr (MODE == 2)
        k_agg_mfma2<T><<<NN / 4, 256, 0, stream>>>(P.dtf, P.ptr, P.nB, P.eaP, mW0, mb0, P.nG);
    else if constexpr (MODE == 1)
        k_agg_mfma<T><<<NN / 4, 256, 0, stream>>>(P.dtf, P.csr, P.ptr, P.nB, P.eaP, mW0, mb0, P.nG);
    else
        k_agg<T><<<NN / 4, 256, 0, stream>>>(P.dtf, P.csr, P.ptr, P.nB, ea, mW0, mb0, P.nG);
    gemm_node<T, 2, 2, 4, true, true><<<GEMM_BLKS, 256, 0, stream>>>(P.dtf, P.nA, P.nG, uW0, ub0, P.nB);

    gemm_node<T, 2, 0, 4, false, false><<<GEMM_BLKS, 256, 0, stream>>>(P.dtf, P.nB, nullptr, mW1, nullptr, P.nA);
    if constexpr (MODE == 2)
        k_agg_mfma2<T><<<NN / 4, 256, 0, stream>>>(P.dtf, P.ptr, P.nA, P.eaP, mW1, mb1, P.nG);
    else if constexpr (MODE == 1)
        k_agg_mfma<T><<<NN / 4, 256, 0, stream>>>(P.dtf, P.csr, P.ptr, P.nA, P.eaP, mW1, mb1, P.nG);
    else
        k_agg<T><<<NN / 4, 256, 0, stream>>>(P.dtf, P.csr, P.ptr, P.nA, ea, mW1, mb1, P.nG);
    gemm_node<T, 2, 2, 4, true, true><<<GEMM_BLKS, 256, 0, stream>>>(P.dtf, P.nB, P.nG, uW1, ub1, P.nA);

    k_mlp_out<T><<<GEMM_BLKS, 256, 0, stream>>>(P.dtf, P.nA, nW1, nb1, nW2, nb2, out);
}

extern "C" void kernel_launch(void* const* d_in, const int* in_sizes, int n_in,
                              void* d_out, int out_size, void* d_ws, size_t ws_size,
                              hipStream_t stream) {
    const int* eix = (const int*)d_in[1];
    char* w = (char*)d_ws;
    (void)out_size;

    // Mode selection by pure size arithmetic (host-constant: graph-safe).
    WSPlan p2 = carve_plan(w, CSTR, (size_t)NE * 64, false);      // ~145 MB
    WSPlan p1 = carve_plan(w, 1, (size_t)NE * ECH * 2, true);     // ~103.5 MB (round-2 verified)
    WSPlan p0 = carve_plan(w, 1, 0, true);                        // ~52.5 MB
    int mode;
    WSPlan P;
    if (p2.used <= ws_size) { mode = 2; P = p2; }
    else if (p1.used <= ws_size) { mode = 1; P = p1; }
    else { mode = 0; P = p0; }

    // Host-side dtype narrowing: only on EXACT byte-size match of emb (100x128).
    // Any other in_sizes convention (e.g. element counts) -> launch both (safe).
    bool doF = true, doB = true;
    if (in_sizes && n_in >= 1) {
        if (in_sizes[0] == NGR * EMBD * 4) doB = false;        // fp32 inputs
        else if (in_sizes[0] == NGR * EMBD * 2) doF = false;   // bf16 inputs
    }

    const int SCAN_BLKS = (NN + 511) / 512;   // 196
    const int GEMM_BLKS = (NN / 16 + 3) / 4;  // 1563

    k_detect<<<1, 64, 0, stream>>>((const unsigned short*)d_in[0], eix, P.dtf);

    // CSR build (dtype-independent part)
    if (mode == 2) {
        k_zero<CSTR><<<(NN + 255) / 256, 256, 0, stream>>>(P.deg);
        k_hist<CSTR><<<NE / 256, 256, 0, stream>>>(eix, P.dtf, P.deg);
        k_scan1<CSTR><<<SCAN_BLKS, 256, 0, stream>>>(P.deg, P.bsum);
        k_scan2<<<1, 256, 0, stream>>>(P.bsum, SCAN_BLKS);
        k_scan3<CSTR><<<SCAN_BLKS, 256, 0, stream>>>(P.deg, P.bsum, P.ptr, P.cur);
    } else {
        k_zero<1><<<(NN + 255) / 256, 256, 0, stream>>>(P.deg);
        k_hist<1><<<NE / 256, 256, 0, stream>>>(eix, P.dtf, P.deg);
        k_scan1<1><<<SCAN_BLKS, 256, 0, stream>>>(P.deg, P.bsum);
        k_scan2<<<1, 256, 0, stream>>>(P.bsum, SCAN_BLKS);
        k_scan3<1><<<SCAN_BLKS, 256, 0, stream>>>(P.deg, P.bsum, P.ptr, P.cur);
        k_fill<1><<<NE / 256, 256, 0, stream>>>(eix, P.dtf, P.cur, P.csr);
    }

    // launch needed dtype variant(s); a wrong one early-exits on dtf[0]
    if (mode == 2) {
        if (doF) launch_typed<float, 2>(d_in, d_out, stream, P, eix, GEMM_BLKS);
        if (doB) launch_typed<unsigned short, 2>(d_in, d_out, stream, P, eix, GEMM_BLKS);
    } else if (mode == 1) {
        if (doF) launch_typed<float, 1>(d_in, d_out, stream, P, eix, GEMM_BLKS);
        if (doB) launch_typed<unsigned short, 1>(d_in, d_out, stream, P, eix, GEMM_BLKS);
    } else {
        if (doF) launch_typed<float, 0>(d_in, d_out, stream, P, eix, GEMM_BLKS);
        if (doB) launch_typed<unsigned short, 0>(d_in, d_out, stream, P, eix, GEMM_BLKS);
    }
}

// Round 6
// 779.719 us; speedup vs baseline: 1.2847x; 1.0290x over previous
//
#include <hip/hip_runtime.h>

// Problem constants (from reference)
#define NN   100000      // nodes
#define NE   1600000     // edges
#define DD   64          // node feature dim
#define ECH  16          // edge channels
#define EMBD 128
#define G1D  512
#define G2D  64000
#define NGR  100         // graphs
#define NM1D 128
// counter stride (ints) for the histogram atomics. Atomic fabric traffic is
// 32B/atomic regardless of stride (round-5 measurement), so stride only
// affects same-line serialization. 4 ints = 4 counters per 64B line.
#define CSTR 4

typedef __attribute__((ext_vector_type(8))) short short8;
typedef __attribute__((ext_vector_type(4))) float float4v;

__device__ __forceinline__ float bf2f(unsigned short u) {
    union { unsigned int i; float f; } v; v.i = ((unsigned int)u) << 16; return v.f;
}
__device__ __forceinline__ unsigned short f2bf(float f) {
    union { unsigned int i; float f; } v; v.f = f;
    unsigned int u = v.i;
    return (unsigned short)((u + 0x7fffu + ((u >> 16) & 1u)) >> 16);
}
__device__ __forceinline__ float blo(unsigned int d) {
    union { unsigned int i; float f; } v; v.i = d << 16; return v.f;
}
__device__ __forceinline__ float bhi(unsigned int d) {
    union { unsigned int i; float f; } v; v.i = d & 0xffff0000u; return v.f;
}
__device__ __forceinline__ int iclamp(int v, int lo, int hi) {
    return v < lo ? lo : (v > hi ? hi : v);
}

// ---- dtype-generic accessors (T = float or unsigned short[bf16]) ----
__device__ __forceinline__ float ldf(const float* p, size_t i) { return p[i]; }
__device__ __forceinline__ float ldf(const unsigned short* p, size_t i) { return bf2f(p[i]); }
__device__ __forceinline__ unsigned short ldbf(const float* p, size_t i) { return f2bf(p[i]); }
__device__ __forceinline__ unsigned short ldbf(const unsigned short* p, size_t i) { return p[i]; }
__device__ __forceinline__ void stf(float* p, size_t i, float v) { p[i] = v; }
__device__ __forceinline__ void stf(unsigned short* p, size_t i, float v) { p[i] = f2bf(v); }
__device__ __forceinline__ void ld16v(const float* p, float* o) {
    const float4* q = (const float4*)p;
    float4 a = q[0], b = q[1], c = q[2], d = q[3];
    o[0]=a.x; o[1]=a.y; o[2]=a.z; o[3]=a.w;
    o[4]=b.x; o[5]=b.y; o[6]=b.z; o[7]=b.w;
    o[8]=c.x; o[9]=c.y; o[10]=c.z; o[11]=c.w;
    o[12]=d.x; o[13]=d.y; o[14]=d.z; o[15]=d.w;
}
__device__ __forceinline__ void ld16v(const unsigned short* p, float* o) {
    const uint4* q = (const uint4*)p;
    uint4 a = q[0], b = q[1];
    o[0]=blo(a.x); o[1]=bhi(a.x); o[2]=blo(a.y); o[3]=bhi(a.y);
    o[4]=blo(a.z); o[5]=bhi(a.z); o[6]=blo(a.w); o[7]=bhi(a.w);
    o[8]=blo(b.x); o[9]=bhi(b.x); o[10]=blo(b.y); o[11]=bhi(b.y);
    o[12]=blo(b.z); o[13]=bhi(b.z); o[14]=blo(b.w); o[15]=bhi(b.w);
}
template <typename T> struct tagof;
template <> struct tagof<float> { static constexpr int v = 0; };
template <> struct tagof<unsigned short> { static constexpr int v = 1; };

#define MFMA(a, b, c) __builtin_amdgcn_mfma_f32_16x16x32_bf16((a), (b), (c), 0, 0, 0)

// ---------------- dtype detect (block 0) + deg zero (all blocks) ----------------
template <int STRIDE>
__global__ __launch_bounds__(256) void k_detect_zero(const unsigned short* __restrict__ embu,
                                                     const int* __restrict__ eidx,
                                                     int* __restrict__ dtf,
                                                     int* __restrict__ deg) {
    int i = blockIdx.x * 256 + threadIdx.x;
    if (i < NN) deg[(size_t)i * STRIDE] = 0;
    if (blockIdx.x == 0 && threadIdx.x < 64) {
        int lane = threadIdx.x;
        int sane = 0;
        for (int k = lane; k < 512; k += 64) {
            unsigned short x = embu[k];
            int e = (x >> 7) & 0xFF;
            if (x == 0 || (e >= 97 && e <= 157)) sane++;
        }
        for (int m = 32; m >= 1; m >>= 1) sane += __shfl_xor(sane, m);
        int oddNZ = 0, evenNZ = 0;
        for (int k = lane; k < 256; k += 64) {
            if (eidx[2 * k + 1] != 0) oddNZ = 1;
            if (eidx[2 * k] != 0) evenNZ = 1;
        }
        unsigned long long bo = __ballot(oddNZ);
        unsigned long long be = __ballot(evenNZ);
        if (lane == 0) {
            dtf[0] = (sane >= 461) ? 1 : 0;
            dtf[1] = (bo == 0ULL && be != 0ULL) ? 1 : 0;
        }
    }
}
__device__ __forceinline__ int ld_src(const int* e, int f, int i) {
    int v = f ? e[2 * i] : e[i];
    return iclamp(v, 0, NN - 1);
}
__device__ __forceinline__ int ld_dst(const int* e, int f, int i) {
    int v = f ? e[2 * (NE + i)] : e[NE + i];
    return iclamp(v, 0, NN - 1);
}

// ---------------- decoder MLP layer 1 ----------------
template <typename T>
__global__ __launch_bounds__(256) void k_dec1(const int* __restrict__ dtf,
                                              const T* __restrict__ emb,
                                              const T* __restrict__ Wg1,
                                              const T* __restrict__ bg1,
                                              unsigned short* __restrict__ h) {
    if (dtf[0] != tagof<T>::v) return;
    __shared__ float es[EMBD];
    int m = blockIdx.x, t = threadIdx.x;
    if (t < EMBD) es[t] = ldf(emb, (size_t)m * EMBD + t);
    __syncthreads();
    for (int n = t; n < G1D; n += 256) {
        float acc = ldf(bg1, n);
        for (int k = 0; k < EMBD; k++) acc += es[k] * ldf(Wg1, (size_t)k * G1D + n);
        h[m * G1D + n] = f2bf(fmaxf(acc, 0.f));
    }
}

// ---------------- decoder MLP layer 2 (MFMA) ----------------
template <typename T>
__global__ __launch_bounds__(256) void k_dec2(const int* __restrict__ dtf,
                                              const unsigned short* __restrict__ h,
                                              const T* __restrict__ Wg2,
                                              const T* __restrict__ bg2,
                                              unsigned short* __restrict__ x) {
    if (dtf[0] != tagof<T>::v) return;
    int wid = threadIdx.x >> 6, lane = threadIdx.x & 63;
    int q = lane >> 4, l16 = lane & 15;
    int n = blockIdx.x * 64 + wid * 16 + l16;
    float4v acc[7];
    for (int mt = 0; mt < 7; mt++) for (int i = 0; i < 4; i++) acc[mt][i] = 0.f;
    for (int kt = 0; kt < 16; kt++) {
        int k0 = kt * 32 + q * 8;
        short8 bf;
        for (int j = 0; j < 8; j++) bf[j] = (short)ldbf(Wg2, (size_t)(k0 + j) * G2D + n);
        for (int mt = 0; mt < 7; mt++) {
            int row = mt * 16 + l16;
            short8 af;
            if (row < NGR) {
                af = *(const short8*)(h + row * G1D + k0);
            } else {
                for (int j = 0; j < 8; j++) af[j] = 0;
            }
            acc[mt] = MFMA(af, bf, acc[mt]);
        }
    }
    float bias = ldf(bg2, n);
    for (int mt = 0; mt < 7; mt++) {
        for (int i = 0; i < 4; i++) {
            int m = mt * 16 + q * 4 + i;
            if (m < NGR) x[(size_t)m * G2D + n] = f2bf(acc[mt][i] + bias);
        }
    }
}

// ---------------- CSR build: ONE atomic pass, rank recorded ----------------
// rank[e] = position of edge e within its dst bucket. Final slot for edge e is
// ptr[dst]+rank[e] -- no atomics needed in the record-writing pass.
template <int STRIDE>
__global__ __launch_bounds__(256) void k_histr(const int* __restrict__ eidx, const int* __restrict__ dtf,
                                               int* __restrict__ deg, int* __restrict__ rank) {
    int e = blockIdx.x * 256 + threadIdx.x;   // grid exact
    int f = dtf[1];
    rank[e] = atomicAdd(&deg[(size_t)ld_dst(eidx, f, e) * STRIDE], 1);
}
template <int STRIDE>
__global__ __launch_bounds__(256) void k_scan1(const int* __restrict__ deg, int* __restrict__ bsum) {
    __shared__ int r[256];
    int t = threadIdx.x, i0 = blockIdx.x * 512 + 2 * t;
    int e0 = (i0 < NN) ? deg[(size_t)i0 * STRIDE] : 0;
    int e1 = (i0 + 1 < NN) ? deg[(size_t)(i0 + 1) * STRIDE] : 0;
    r[t] = e0 + e1;
    __syncthreads();
    for (int off = 128; off > 0; off >>= 1) {
        if (t < off) r[t] += r[t + off];
        __syncthreads();
    }
    if (t == 0) bsum[blockIdx.x] = r[0];
}
// merged scan2+scan3: each block redundantly scans all block sums in LDS
// (nblk <= 256), then does its local 512-element scan. No cur array.
template <int STRIDE>
__global__ __launch_bounds__(256) void k_scan3m(const int* __restrict__ deg, const int* __restrict__ bsum,
                                                int nblk, int* __restrict__ ptr) {
    __shared__ int sc[256];
    int t = threadIdx.x;
    // 1) exclusive prefix of block sums up to this block
    int bv = (t < nblk) ? bsum[t] : 0;
    sc[t] = bv;
    __syncthreads();
    for (int off = 1; off < 256; off <<= 1) {
        int u = (t >= off) ? sc[t - off] : 0;
        __syncthreads();
        sc[t] += u;
        __syncthreads();
    }
    int base = sc[blockIdx.x] - ((blockIdx.x < nblk) ? bsum[blockIdx.x] : 0);
    __syncthreads();
    // 2) local scan over this block's 512 degrees
    int i0 = blockIdx.x * 512 + 2 * t;
    int e0 = (i0 < NN) ? deg[(size_t)i0 * STRIDE] : 0;
    int e1 = (i0 + 1 < NN) ? deg[(size_t)(i0 + 1) * STRIDE] : 0;
    int s = e0 + e1;
    sc[t] = s;
    __syncthreads();
    for (int off = 1; off < 256; off <<= 1) {
        int v = (t >= off) ? sc[t - off] : 0;
        __syncthreads();
        sc[t] += v;
        __syncthreads();
    }
    int excl = sc[t] - s;
    int p0 = base + excl;
    if (i0 < NN)     ptr[i0] = p0;
    if (i0 + 1 < NN) ptr[i0 + 1] = p0 + e0;
    if (blockIdx.x == 0 && t == 0) ptr[NN] = NE;
}
// MODE<=1: csr.x stores the Y-ROW BYTE OFFSET (clamped src * DD * 2). Atomic-free.
__global__ __launch_bounds__(256) void k_fillr(const int* __restrict__ eidx, const int* __restrict__ dtf,
                                               const int* __restrict__ ptr, const int* __restrict__ rank,
                                               int2* __restrict__ csr) {
    int e = blockIdx.x * 256 + threadIdx.x;   // grid exact
    int f = dtf[1];
    int src = ld_src(eidx, f, e);
    int dst = ld_dst(eidx, f, e);
    int pos = iclamp(ptr[dst] + rank[e], 0, NE - 1);
    csr[pos] = make_int2(src * (DD * 2), e);
}

// MODE==2: fused fill+permute, ATOMIC-FREE. 64B record per CSR slot:
//   shorts [0,16): bf16 edge_attr row   int @byte32: src y-row byte offset   rest: pad
// ea read COALESCED (thread e reads row e); write one FULL 64B line; pos from ptr+rank.
template <typename T>
__global__ __launch_bounds__(256) void k_fill3(const int* __restrict__ eidx, const int* __restrict__ dtf,
                                               const T* __restrict__ ea,
                                               const int* __restrict__ ptr, const int* __restrict__ rank,
                                               uint4* __restrict__ rows) {
    if (dtf[0] != tagof<T>::v) return;
    int e = blockIdx.x * 256 + threadIdx.x;   // grid exact
    int f = dtf[1];
    int src = ld_src(eidx, f, e);
    int dst = ld_dst(eidx, f, e);
    float ev[16];
    ld16v(ea + (size_t)e * ECH, ev);
    unsigned int wv[8];
    #pragma unroll
    for (int i = 0; i < 8; i++)
        wv[i] = (unsigned int)f2bf(ev[2 * i]) | ((unsigned int)f2bf(ev[2 * i + 1]) << 16);
    int pos = iclamp(ptr[dst] + rank[e], 0, NE - 1);   // ptr: 400KB, L2-resident
    uint4* r = rows + (size_t)pos * 4;
    r[0] = make_uint4(wv[0], wv[1], wv[2], wv[3]);
    r[1] = make_uint4(wv[4], wv[5], wv[6], wv[7]);
    r[2] = make_uint4((unsigned int)(src * (DD * 2)), 0u, 0u, 0u);
    r[3] = make_uint4(0u, 0u, 0u, 0u);   // full-line write
}

// ---------------- permute edge_attr into CSR order (MODE==1) ----------------
template <typename T>
__global__ __launch_bounds__(256) void k_eaperm(const int* __restrict__ dtf,
                                                const int2* __restrict__ csr,
                                                const T* __restrict__ ea,
                                                unsigned short* __restrict__ eaP) {
    if (dtf[0] != tagof<T>::v) return;
    int p = blockIdx.x * 256 + threadIdx.x;   // grid exact: NE/256
    int eid = iclamp(csr[p].y, 0, NE - 1);
    float ev[16];
    ld16v(ea + (size_t)eid * ECH, ev);
    unsigned int wv[8];
    for (int i = 0; i < 8; i++)
        wv[i] = (unsigned int)f2bf(ev[2 * i]) | ((unsigned int)f2bf(ev[2 * i + 1]) << 16);
    uint4* op = (uint4*)(eaP + (size_t)p * ECH);
    op[0] = make_uint4(wv[0], wv[1], wv[2], wv[3]);
    op[1] = make_uint4(wv[4], wv[5], wv[6], wv[7]);
}

// ---------------- MFMA edge aggregation, MODE==2 (64B rows, single stream) ----------
// Fragment maps identical to gemm_node (harness-verified):
//   A: row=l16, k=q*8+j   B: k=q*8+j, col=l16   D: row=q*4+i, col=l16
template <typename T>
__global__ __launch_bounds__(256) void k_agg_mfma2(const int* __restrict__ dtf,
                                                   const int* __restrict__ ptr,
                                                   const unsigned short* __restrict__ y,
                                                   const unsigned short* __restrict__ rows,
                                                   const T* __restrict__ mW,
                                                   const T* __restrict__ mb,
                                                   unsigned short* __restrict__ agg) {
    if (dtf[0] != tagof<T>::v) return;
    int nid = blockIdx.x * 4 + (threadIdx.x >> 6);
    int lane = threadIdx.x & 63;
    int q = lane >> 4, l16 = lane & 15;

    short8 bfr[4];
    #pragma unroll
    for (int nt = 0; nt < 4; nt++) {
        short8 b;
        #pragma unroll
        for (int j = 0; j < 8; j++) b[j] = 0;
        if (q < 2) {
            #pragma unroll
            for (int j = 0; j < 8; j++)
                b[j] = (short)ldbf(mW, (size_t)(DD + q * 8 + j) * DD + nt * 16 + l16);
        }
        bfr[nt] = b;
    }
    float mbc[4];
    #pragma unroll
    for (int nt = 0; nt < 4; nt++) mbc[nt] = ldf(mb, nt * 16 + l16);

    int s = iclamp(ptr[nid], 0, NE);
    int e = iclamp(ptr[nid + 1], s, NE);

    float acc[4] = {0.f, 0.f, 0.f, 0.f};
    const float4v z4 = {0.f, 0.f, 0.f, 0.f};

    for (int t = s; t < e; t += 16) {
        short8 af;
        #pragma unroll
        for (int j = 0; j < 8; j++) af[j] = 0;
        int erow = t + l16;
        if (erow < e && q < 2)
            af = *(const short8*)(rows + (size_t)erow * 32 + q * 8);

        int off[4]; bool val[4];
        #pragma unroll
        for (int i = 0; i < 4; i++) {
            int idx = t + q * 4 + i;
            val[i] = idx < e;
            int cidx = idx < e ? idx : (e - 1);
            off[i] = *(const int*)(rows + (size_t)cidx * 32 + 16);   // byte 32 of the row
        }

        #pragma unroll
        for (int nt = 0; nt < 4; nt++) {
            float4v p = MFMA(af, bfr[nt], z4);
            int colb = (nt * 16 + l16) * 2;
            #pragma unroll
            for (int i = 0; i < 4; i++) {
                float yv = bf2f(*(const unsigned short*)((const char*)y + (unsigned int)(off[i] + colb)));
                float z = fmaxf(p[i] + yv + mbc[nt], 0.f);
                acc[nt] += val[i] ? z : 0.f;
            }
        }
    }

    #pragma unroll
    for (int nt = 0; nt < 4; nt++) {
        acc[nt] += __shfl_xor(acc[nt], 16);
        acc[nt] += __shfl_xor(acc[nt], 32);
    }
    float r = (q == 0) ? acc[0] : (q == 1) ? acc[1] : (q == 2) ? acc[2] : acc[3];
    agg[(size_t)nid * DD + lane] = f2bf(r);
}

// ---------------- MFMA edge aggregation, MODE==1 (eaP32 + csr) ----------------
template <typename T>
__global__ __launch_bounds__(256) void k_agg_mfma(const int* __restrict__ dtf,
                                                  const int2* __restrict__ csr,
                                                  const int* __restrict__ ptr,
                                                  const unsigned short* __restrict__ y,
                                                  const unsigned short* __restrict__ eaP,
                                                  const T* __restrict__ mW,
                                                  const T* __restrict__ mb,
                                                  unsigned short* __restrict__ agg) {
    if (dtf[0] != tagof<T>::v) return;
    int nid = blockIdx.x * 4 + (threadIdx.x >> 6);
    int lane = threadIdx.x & 63;
    int q = lane >> 4, l16 = lane & 15;

    short8 bfr[4];
    #pragma unroll
    for (int nt = 0; nt < 4; nt++) {
        short8 b;
        #pragma unroll
        for (int j = 0; j < 8; j++) b[j] = 0;
        if (q < 2) {
            #pragma unroll
            for (int j = 0; j < 8; j++)
                b[j] = (short)ldbf(mW, (size_t)(DD + q * 8 + j) * DD + nt * 16 + l16);
        }
        bfr[nt] = b;
    }
    float mbc[4];
    #pragma unroll
    for (int nt = 0; nt < 4; nt++) mbc[nt] = ldf(mb, nt * 16 + l16);

    int s = iclamp(ptr[nid], 0, NE);
    int e = iclamp(ptr[nid + 1], s, NE);

    float acc[4] = {0.f, 0.f, 0.f, 0.f};
    const float4v z4 = {0.f, 0.f, 0.f, 0.f};

    for (int t = s; t < e; t += 16) {
        short8 af;
        #pragma unroll
        for (int j = 0; j < 8; j++) af[j] = 0;
        int erow = t + l16;
        if (erow < e && q < 2)
            af = *(const short8*)(eaP + (size_t)erow * ECH + q * 8);

        int off[4]; bool val[4];
        #pragma unroll
        for (int i = 0; i < 4; i++) {
            int idx = t + q * 4 + i;
            val[i] = idx < e;
            int cidx = idx < e ? idx : (e - 1);
            off[i] = csr[cidx].x;
        }

        #pragma unroll
        for (int nt = 0; nt < 4; nt++) {
            float4v p = MFMA(af, bfr[nt], z4);
            int colb = (nt * 16 + l16) * 2;
            #pragma unroll
            for (int i = 0; i < 4; i++) {
                float yv = bf2f(*(const unsigned short*)((const char*)y + (unsigned int)(off[i] + colb)));
                float z = fmaxf(p[i] + yv + mbc[nt], 0.f);
                acc[nt] += val[i] ? z : 0.f;
            }
        }
    }

    #pragma unroll
    for (int nt = 0; nt < 4; nt++) {
        acc[nt] += __shfl_xor(acc[nt], 16);
        acc[nt] += __shfl_xor(acc[nt], 32);
    }
    float r = (q == 0) ? acc[0] : (q == 1) ? acc[1] : (q == 2) ? acc[2] : acc[3];
    agg[(size_t)nid * DD + lane] = f2bf(r);
}

// ---------------- scalar edge aggregation (MODE==0 fallback) ----------------
template <typename T>
__global__ __launch_bounds__(256) void k_agg(const int* __restrict__ dtf,
                                             const int2* __restrict__ csr, const int* __restrict__ ptr,
                                             const unsigned short* __restrict__ y,
                                             const T* __restrict__ ea,
                                             const T* __restrict__ mW,
                                             const T* __restrict__ mb,
                                             unsigned short* __restrict__ agg) {
    if (dtf[0] != tagof<T>::v) return;
    int nid = blockIdx.x * 4 + (threadIdx.x >> 6);
    int lane = threadIdx.x & 63;
    float wk[16];
    for (int k = 0; k < 16; k++) wk[k] = ldf(mW, (size_t)(DD + k) * DD + lane);
    float mbv = ldf(mb, lane);
    int s = iclamp(ptr[nid], 0, NE);
    int e = iclamp(ptr[nid + 1], s, NE);
    const char* yl = (const char*)y + (size_t)lane * 2;
    float acc = 0.f;
    int t = s;
    for (; t + 2 <= e; t += 2) {
        int2 p0 = csr[t], p1 = csr[t + 1];
        float y0 = bf2f(*(const unsigned short*)(yl + (unsigned int)p0.x));
        float y1 = bf2f(*(const unsigned short*)(yl + (unsigned int)p1.x));
        float e0[16], e1[16];
        ld16v(ea + (size_t)iclamp(p0.y, 0, NE - 1) * ECH, e0);
        ld16v(ea + (size_t)iclamp(p1.y, 0, NE - 1) * ECH, e1);
        float z0 = mbv + y0, z1 = mbv + y1;
        #pragma unroll
        for (int k = 0; k < 16; k++) { z0 = fmaf(e0[k], wk[k], z0); z1 = fmaf(e1[k], wk[k], z1); }
        acc += fmaxf(z0, 0.f) + fmaxf(z1, 0.f);
    }
    for (; t < e; ++t) {
        int2 p = csr[t];
        float yv = bf2f(*(const unsigned short*)(yl + (unsigned int)p.x));
        float ev[16];
        ld16v(ea + (size_t)iclamp(p.y, 0, NE - 1) * ECH, ev);
        float z = mbv + yv;
        #pragma unroll
        for (int k = 0; k < 16; k++) z = fmaf(ev[k], wk[k], z);
        acc += fmaxf(z, 0.f);
    }
    agg[(size_t)nid * DD + lane] = f2bf(acc);
}

// ---------------- generic skinny MFMA GEMM over node rows ----------------
template <typename T, int KT1, int KT2, int NT, bool RELU, bool HASBIAS>
__global__ __launch_bounds__(256) void gemm_node(const int* __restrict__ dtf,
                                                 const unsigned short* __restrict__ A1,
                                                 const unsigned short* __restrict__ A2,
                                                 const T* __restrict__ W,
                                                 const T* __restrict__ bias,
                                                 unsigned short* __restrict__ out) {
    if (dtf[0] != tagof<T>::v) return;
    constexpr int KT = KT1 + KT2;
    constexpr int N = NT * 16;
    int wid = threadIdx.x >> 6, lane = threadIdx.x & 63;
    int q = lane >> 4, l16 = lane & 15;
    int mt = blockIdx.x * 4 + wid;
    int m0 = mt * 16;
    if (m0 >= NN) return;
    short8 bfr[KT][NT];
    for (int kt = 0; kt < KT; kt++)
        for (int nt = 0; nt < NT; nt++)
            for (int j = 0; j < 8; j++)
                bfr[kt][nt][j] = (short)ldbf(W, (size_t)(kt * 32 + q * 8 + j) * N + nt * 16 + l16);
    float4v acc[NT];
    for (int nt = 0; nt < NT; nt++) for (int i = 0; i < 4; i++) acc[nt][i] = 0.f;

    const unsigned short* a1p = A1 + (size_t)(m0 + l16) * (KT1 * 32) + q * 8;
    for (int kt = 0; kt < KT1; kt++) {
        short8 af = *(const short8*)(a1p + kt * 32);
        for (int nt = 0; nt < NT; nt++) acc[nt] = MFMA(af, bfr[kt][nt], acc[nt]);
    }
    if constexpr (KT2 > 0) {
        const unsigned short* a2p = A2 + (size_t)(m0 + l16) * (KT2 * 32) + q * 8;
        for (int kt = 0; kt < KT2; kt++) {
            short8 af = *(const short8*)(a2p + kt * 32);
            for (int nt = 0; nt < NT; nt++) acc[nt] = MFMA(af, bfr[KT1 + kt][nt], acc[nt]);
        }
    }
    for (int nt = 0; nt < NT; nt++) {
        int n = nt * 16 + l16;
        float b = HASBIAS ? ldf(bias, n) : 0.f;
        for (int i = 0; i < 4; i++) {
            float v = acc[nt][i] + b;
            if (RELU) v = fmaxf(v, 0.f);
            out[(size_t)(m0 + q * 4 + i) * N + n] = f2bf(v);
        }
    }
}

// ---------------- fused node MLP ----------------
template <typename T>
__global__ __launch_bounds__(256) void k_mlp_out(const int* __restrict__ dtf,
                                                 const unsigned short* __restrict__ A,
                                                 const T* __restrict__ nW1,
                                                 const T* __restrict__ nb1,
                                                 const T* __restrict__ nW2,
                                                 const T* __restrict__ nb2,
                                                 T* __restrict__ out) {
    if (dtf[0] != tagof<T>::v) return;
    constexpr int NT = 8, N = 128;
    int wid = threadIdx.x >> 6, lane = threadIdx.x & 63;
    int q = lane >> 4, l16 = lane & 15;
    int mt = blockIdx.x * 4 + wid;
    int m0 = mt * 16;
    if (m0 >= NN) return;
    short8 bfr[2][NT];
    float cb[NT], w2r[NT][3];
    for (int kt = 0; kt < 2; kt++)
        for (int nt = 0; nt < NT; nt++)
            for (int j = 0; j < 8; j++)
                bfr[kt][nt][j] = (short)ldbf(nW1, (size_t)(kt * 32 + q * 8 + j) * N + nt * 16 + l16);
    for (int nt = 0; nt < NT; nt++) {
        int col = nt * 16 + l16;
        cb[nt] = ldf(nb1, col);
        for (int j = 0; j < 3; j++) w2r[nt][j] = ldf(nW2, (size_t)col * 3 + j);
    }
    float4v acc[NT];
    for (int nt = 0; nt < NT; nt++) for (int i = 0; i < 4; i++) acc[nt][i] = 0.f;
    const unsigned short* ap = A + (size_t)(m0 + l16) * DD + q * 8;
    for (int kt = 0; kt < 2; kt++) {
        short8 af = *(const short8*)(ap + kt * 32);
        for (int nt = 0; nt < NT; nt++) acc[nt] = MFMA(af, bfr[kt][nt], acc[nt]);
    }
    float b0 = ldf(nb2, 0), b1 = ldf(nb2, 1), b2 = ldf(nb2, 2);
    for (int i = 0; i < 4; i++) {
        float p0 = 0.f, p1 = 0.f, p2 = 0.f;
        for (int nt = 0; nt < 8; nt++) {
            float v = fmaxf(acc[nt][i] + cb[nt], 0.f);
            p0 += v * w2r[nt][0];
            p1 += v * w2r[nt][1];
            p2 += v * w2r[nt][2];
        }
        for (int m = 1; m < 16; m <<= 1) {
            p0 += __shfl_xor(p0, m);
            p1 += __shfl_xor(p1, m);
            p2 += __shfl_xor(p2, m);
        }
        if (l16 == 0) {
            size_t row = (size_t)(m0 + q * 4 + i) * 3;
            stf(out, row + 0, p0 + b0);
            stf(out, row + 1, p1 + b1);
            stf(out, row + 2, p2 + b2);
        }
    }
}

// ---------------- workspace plan ----------------
struct WSPlan {
    unsigned short *nA, *nB, *nG, *hb, *eaP;
    int2* csr;
    int *deg, *ptr, *rank, *bsum, *dtf;
    size_t used;
};
static WSPlan carve_plan(char* w, int stride, size_t eaBytes, bool needCsr) {
    WSPlan r;
    size_t off = 0;
    auto cv = [&](size_t b) -> char* { char* p = w + off; off = (off + b + 255) & ~(size_t)255; return p; };
    r.nA  = (unsigned short*)cv((size_t)NN * DD * 2);            // 12.8 MB
    r.nB  = (unsigned short*)cv((size_t)NN * DD * 2);            // 12.8 MB
    r.nG  = (unsigned short*)cv((size_t)NN * DD * 2);            // 12.8 MB
    r.csr = needCsr ? (int2*)cv((size_t)NE * 8) : nullptr;       // 12.8 MB (modes 0/1)
    r.hb  = (unsigned short*)cv((size_t)NGR * G1D * 2);          // 0.1 MB
    r.deg = (int*)cv((size_t)NN * stride * 4);
    r.ptr = (int*)cv((size_t)(NN + 1) * 4);
    r.rank = (int*)cv((size_t)NE * 4);                           // 6.4 MB
    r.bsum = (int*)cv((size_t)256 * 4);
    r.dtf  = (int*)cv(256);
    r.eaP = eaBytes ? (unsigned short*)cv(eaBytes) : nullptr;
    r.used = off;
    return r;
}

// ---------------- typed pipeline launcher ----------------
// MODE: 2 = fused 64B rows (atomic-free fill), 1 = eaP32 + csr, 0 = scalar
template <typename T, int MODE>
static void launch_typed(void* const* d_in, void* d_out, hipStream_t stream,
                         const WSPlan& P, const int* eix, int GEMM_BLKS) {
    const T* emb = (const T*)d_in[0];
    const T* ea  = (const T*)d_in[2];
    const T* Wg1 = (const T*)d_in[3];  const T* bg1 = (const T*)d_in[4];
    const T* Wg2 = (const T*)d_in[5];  const T* bg2 = (const T*)d_in[6];
    const T* mW0 = (const T*)d_in[7];  const T* mb0 = (const T*)d_in[8];
    const T* uW0 = (const T*)d_in[9];  const T* ub0 = (const T*)d_in[10];
    const T* mW1 = (const T*)d_in[11]; const T* mb1 = (const T*)d_in[12];
    const T* uW1 = (const T*)d_in[13]; const T* ub1 = (const T*)d_in[14];
    const T* nW1 = (const T*)d_in[15]; const T* nb1 = (const T*)d_in[16];
    const T* nW2 = (const T*)d_in[17]; const T* nb2 = (const T*)d_in[18];
    T* out = (T*)d_out;

    if constexpr (MODE == 2)
        k_fill3<T><<<NE / 256, 256, 0, stream>>>(eix, P.dtf, ea, P.ptr, P.rank, (uint4*)P.eaP);

    k_dec1<T><<<NGR, 256, 0, stream>>>(P.dtf, emb, Wg1, bg1, P.hb);
    k_dec2<T><<<G2D / 64, 256, 0, stream>>>(P.dtf, P.hb, Wg2, bg2, P.nA);

    if constexpr (MODE == 1)
        k_eaperm<T><<<NE / 256, 256, 0, stream>>>(P.dtf, P.csr, ea, P.eaP);

    gemm_node<T, 2, 0, 4, false, false><<<GEMM_BLKS, 256, 0, stream>>>(P.dtf, P.nA, nullptr, mW0, nullptr, P.nB);
    if constexpr (MODE == 2)
        k_agg_mfma2<T><<<NN / 4, 256, 0, stream>>>(P.dtf, P.ptr, P.nB, P.eaP, mW0, mb0, P.nG);
    else if constexpr (MODE == 1)
        k_agg_mfma<T><<<NN / 4, 256, 0, stream>>>(P.dtf, P.csr, P.ptr, P.nB, P.eaP, mW0, mb0, P.nG);
    else
        k_agg<T><<<NN / 4, 256, 0, stream>>>(P.dtf, P.csr, P.ptr, P.nB, ea, mW0, mb0, P.nG);
    gemm_node<T, 2, 2, 4, true, true><<<GEMM_BLKS, 256, 0, stream>>>(P.dtf, P.nA, P.nG, uW0, ub0, P.nB);

    gemm_node<T, 2, 0, 4, false, false><<<GEMM_BLKS, 256, 0, stream>>>(P.dtf, P.nB, nullptr, mW1, nullptr, P.nA);
    if constexpr (MODE == 2)
        k_agg_mfma2<T><<<NN / 4, 256, 0, stream>>>(P.dtf, P.ptr, P.nA, P.eaP, mW1, mb1, P.nG);
    else if constexpr (MODE == 1)
        k_agg_mfma<T><<<NN / 4, 256, 0, stream>>>(P.dtf, P.csr, P.ptr, P.nA, P.eaP, mW1, mb1, P.nG);
    else
        k_agg<T><<<NN / 4, 256, 0, stream>>>(P.dtf, P.csr, P.ptr, P.nA, ea, mW1, mb1, P.nG);
    gemm_node<T, 2, 2, 4, true, true><<<GEMM_BLKS, 256, 0, stream>>>(P.dtf, P.nB, P.nG, uW1, ub1, P.nA);

    k_mlp_out<T><<<GEMM_BLKS, 256, 0, stream>>>(P.dtf, P.nA, nW1, nb1, nW2, nb2, out);
}

extern "C" void kernel_launch(void* const* d_in, const int* in_sizes, int n_in,
                              void* d_out, int out_size, void* d_ws, size_t ws_size,
                              hipStream_t stream) {
    const int* eix = (const int*)d_in[1];
    char* w = (char*)d_ws;
    (void)out_size;

    // Mode selection by pure size arithmetic (host-constant: graph-safe).
    WSPlan p2 = carve_plan(w, CSTR, (size_t)NE * 64, false);      // ~151 MB
    WSPlan p1 = carve_plan(w, 1, (size_t)NE * ECH * 2, true);     // ~110 MB
    WSPlan p0 = carve_plan(w, 1, 0, true);                        // ~59 MB
    int mode;
    WSPlan P;
    if (p2.used <= ws_size) { mode = 2; P = p2; }
    else if (p1.used <= ws_size) { mode = 1; P = p1; }
    else { mode = 0; P = p0; }

    // Host-side dtype narrowing: only on EXACT byte-size match of emb (100x128).
    bool doF = true, doB = true;
    if (in_sizes && n_in >= 1) {
        if (in_sizes[0] == NGR * EMBD * 4) doB = false;        // fp32 inputs
        else if (in_sizes[0] == NGR * EMBD * 2) doF = false;   // bf16 inputs
    }

    const int SCAN_BLKS = (NN + 511) / 512;   // 196
    const int GEMM_BLKS = (NN / 16 + 3) / 4;  // 1563

    // CSR build: detect+zero -> single atomic pass (ranks) -> scans -> atomic-free fill
    if (mode == 2) {
        k_detect_zero<CSTR><<<(NN + 255) / 256, 256, 0, stream>>>((const unsigned short*)d_in[0], eix, P.dtf, P.deg);
        k_histr<CSTR><<<NE / 256, 256, 0, stream>>>(eix, P.dtf, P.deg, P.rank);
        k_scan1<CSTR><<<SCAN_BLKS, 256, 0, stream>>>(P.deg, P.bsum);
        k_scan3m<CSTR><<<SCAN_BLKS, 256, 0, stream>>>(P.deg, P.bsum, SCAN_BLKS, P.ptr);
    } else {
        k_detect_zero<1><<<(NN + 255) / 256, 256, 0, stream>>>((const unsigned short*)d_in[0], eix, P.dtf, P.deg);
        k_histr<1><<<NE / 256, 256, 0, stream>>>(eix, P.dtf, P.deg, P.rank);
        k_scan1<1><<<SCAN_BLKS, 256, 0, stream>>>(P.deg, P.bsum);
        k_scan3m<1><<<SCAN_BLKS, 256, 0, stream>>>(P.deg, P.bsum, SCAN_BLKS, P.ptr);
        k_fillr<<<NE / 256, 256, 0, stream>>>(eix, P.dtf, P.ptr, P.rank, P.csr);
    }

    // launch needed dtype variant(s); a wrong one early-exits on dtf[0]
    if (mode == 2) {
        if (doF) launch_typed<float, 2>(d_in, d_out, stream, P, eix, GEMM_BLKS);
        if (doB) launch_typed<unsigned short, 2>(d_in, d_out, stream, P, eix, GEMM_BLKS);
    } else if (mode == 1) {
        if (doF) launch_typed<float, 1>(d_in, d_out, stream, P, eix, GEMM_BLKS);
        if (doB) launch_typed<unsigned short, 1>(d_in, d_out, stream, P, eix, GEMM_BLKS);
    } else {
        if (doF) launch_typed<float, 0>(d_in, d_out, stream, P, eix, GEMM_BLKS);
        if (doB) launch_typed<unsigned short, 0>(d_in, d_out, stream, P, eix, GEMM_BLKS);
    }
}